// Round 7
// baseline (695.152 us; speedup 1.0000x reference)
//
#include <hip/hip_runtime.h>
#include <hip/hip_bf16.h>
#include <math.h>

typedef __hip_bfloat16 bf16;
typedef __attribute__((ext_vector_type(8))) short bf16x8;
typedef __attribute__((ext_vector_type(4))) float f32x4;

__device__ __forceinline__ unsigned short f2bf_rne(float f) {
  unsigned u = __float_as_uint(f);
  u += 0x7fffu + ((u >> 16) & 1u);
  return (unsigned short)(u >> 16);
}
__device__ __forceinline__ float bf2f(unsigned short s) {
  return __uint_as_float(((unsigned)s) << 16);
}

// fast tanh-form GELU: max |diff| vs exact erf-GELU ~1e-3
__device__ __forceinline__ float gelu_fast(float v) {
  float u = v * (0.7978845608f + 0.0356774081f * v * v);
  float t = __builtin_amdgcn_exp2f(u * 2.8853900818f);
  float r = __builtin_amdgcn_rcpf(t + 1.0f);
  return v - v * r;
}

#define GLOBAL_AS __attribute__((address_space(1)))
#define LDS_AS __attribute__((address_space(3)))
__device__ __forceinline__ void gl2lds16(const void* g, void* l) {
  __builtin_amdgcn_global_load_lds((const GLOBAL_AS void*)g, (LDS_AS void*)l, 16, 0, 0);
}

// T1: XCD-chunked bijective swizzle (nwg % 8 == 0).
__device__ __forceinline__ int swz8(int f, int nwg) {
  return (f & 7) * (nwg >> 3) + (f >> 3);
}

// ---------------- LayerNorm body: x f32 [row][1024] -> h bf16 ----------------
__device__ __forceinline__ void ln_body(const float* __restrict__ x,
                                        const float* __restrict__ g,
                                        const float* __restrict__ b,
                                        bf16* __restrict__ h, int row, int t) {
  const float4 xv = ((const float4*)(x + (size_t)row * 1024))[t];
  float s = xv.x + xv.y + xv.z + xv.w;
  float sq = xv.x * xv.x + xv.y * xv.y + xv.z * xv.z + xv.w * xv.w;
  #pragma unroll
  for (int m = 1; m < 64; m <<= 1) { s += __shfl_xor(s, m); sq += __shfl_xor(sq, m); }
  __shared__ float ps[4], pq[4];
  if ((t & 63) == 0) { ps[t >> 6] = s; pq[t >> 6] = sq; }
  __syncthreads();
  s = ps[0] + ps[1] + ps[2] + ps[3];
  sq = pq[0] + pq[1] + pq[2] + pq[3];
  float mean = s * (1.0f / 1024.0f);
  float var = sq * (1.0f / 1024.0f) - mean * mean;
  float rs = rsqrtf(var + 1e-3f);
  float4 gv = ((const float4*)g)[t];
  float4 bv = ((const float4*)b)[t];
  ushort4 o;
  o.x = f2bf_rne((xv.x - mean) * rs * gv.x + bv.x);
  o.y = f2bf_rne((xv.y - mean) * rs * gv.y + bv.y);
  o.z = f2bf_rne((xv.z - mean) * rs * gv.z + bv.z);
  o.w = f2bf_rne((xv.w - mean) * rs * gv.w + bv.w);
  ((ushort4*)(h + (size_t)row * 1024))[t] = o;
}

// ------------- merged transpose + f32->bf16 for all 5 weights -------------
__device__ __forceinline__ void tr_tile(const float* __restrict__ W, bf16* __restrict__ WT,
                                        int R, int Cc, int bx, int by, int t) {
  __shared__ float tile[32][33];
  int tx = t & 31, ty = t >> 5;
  #pragma unroll
  for (int k = 0; k < 4; k++) {
    int rr = ty + k * 8;
    tile[rr][tx] = W[(size_t)(by + rr) * Cc + bx + tx];
  }
  __syncthreads();
  unsigned short* out = reinterpret_cast<unsigned short*>(WT);
  #pragma unroll
  for (int k = 0; k < 4; k++) {
    int rr = ty + k * 8;
    out[(size_t)(bx + rr) * R + by + tx] = f2bf_rne(tile[tx][rr]);
  }
}

// --- fused prep: zero fusion counters + ln1 (blocks 0..4095) + transposes ---
__global__ __launch_bounds__(256) void prep_fused(const float* __restrict__ x,
                                                  const float* __restrict__ ln1g,
                                                  const float* __restrict__ ln1b,
                                                  bf16* __restrict__ h,
                                                  const float* __restrict__ Wq,
                                                  const float* __restrict__ Wk,
                                                  const float* __restrict__ Wv,
                                                  const float* __restrict__ W1,
                                                  const float* __restrict__ W2,
                                                  bf16* __restrict__ WqkT,
                                                  bf16* __restrict__ W1T,
                                                  bf16* __restrict__ W2T,
                                                  int* __restrict__ cnt) {
  int id = blockIdx.x, t = threadIdx.x;
  if (id == 0 && t < 128) cnt[t] = 0;   // 64 attn-ln2 + 64 ffn2-reduce counters
  if (id < 4096) { ln_body(x, ln1g, ln1b, h, id, t); return; }
  id -= 4096;
  if (id < 3072) {
    int sect = id >> 10, r = id & 1023;
    const float* W = sect == 0 ? Wq : (sect == 1 ? Wk : Wv);
    bf16* WT = WqkT + (size_t)sect * 1048576;
    tr_tile(W, WT, 1024, 1024, (r & 31) * 32, (r >> 5) * 32, t);
  } else if (id < 7168) {
    int r = id - 3072;
    tr_tile(W1, W1T, 1024, 4096, (r & 127) * 32, (r >> 7) * 32, t);
  } else {
    int r = id - 7168;
    tr_tile(W2, W2T, 4096, 1024, (r & 31) * 32, (r >> 5) * 32, t);
  }
}

// ============ 256x256 8-phase GEMM mainloop (T2+T3+T4+T5) ============
// (unchanged; see round-1 comment block for schedule derivation)
__device__ __forceinline__ void mainloop_256(const bf16* __restrict__ A,
                                             const bf16* __restrict__ BT,
                                             int lda, int nk, int m0, int n0,
                                             char* ldsb, int t,
                                             f32x4 (&acc)[8][4]) {
  const int lane = t & 63, wave = t >> 6;
  const int l = lane & 15, quad = lane >> 4;
  const int wm = (wave >> 2) * 128, wn = (wave & 3) * 64;
  const int srow = wave * 8 + (lane >> 3);          // row within 64-row round
  const int scol = ((lane & 7) ^ (lane >> 3)) * 8;  // pre-swizzled global col
  const int grp0 = (quad ^ (l & 7)) * 16;           // swizzled 16B group, k-slice 0
  const int grp1 = ((4 + quad) ^ (l & 7)) * 16;     // k-slice 1

  bf16x8 a[4][2], b01[2][2], b23[2][2];

  auto stA = [&](int buf, int half, int kt) {
    const bf16* s = A + (size_t)(m0 + half * 128 + srow) * lda + kt * 64 + scol;
    char* d = ldsb + buf * 65536 + half * 16384 + wave * 1024;
    gl2lds16(s, d);
    gl2lds16(s + (size_t)64 * lda, d + 8192);
  };
  auto stB = [&](int buf, int half, int kt) {
    const bf16* s = BT + (size_t)(n0 + half * 128 + srow) * lda + kt * 64 + scol;
    char* d = ldsb + buf * 65536 + 32768 + half * 16384 + wave * 1024;
    gl2lds16(s, d);
    gl2lds16(s + (size_t)64 * lda, d + 8192);
  };
  auto rdA = [&](int buf, int mh) {
    const char* base = ldsb + buf * 65536 + (wm + mh * 64 + l) * 128;
    #pragma unroll
    for (int ii = 0; ii < 4; ii++) {
      a[ii][0] = *(const bf16x8*)(base + ii * 2048 + grp0);
      a[ii][1] = *(const bf16x8*)(base + ii * 2048 + grp1);
    }
  };
  auto rdB = [&](int buf, int nh, bf16x8 (&bb)[2][2]) {
    const char* base = ldsb + buf * 65536 + 32768 + (wn + nh * 32 + l) * 128;
    #pragma unroll
    for (int jj = 0; jj < 2; jj++) {
      bb[jj][0] = *(const bf16x8*)(base + jj * 2048 + grp0);
      bb[jj][1] = *(const bf16x8*)(base + jj * 2048 + grp1);
    }
  };
  auto mm4 = [&](int mi, bf16x8 (&bb)[2][2], int nj) {
    #pragma unroll
    for (int ii = 0; ii < 4; ii++)
      #pragma unroll
      for (int jj = 0; jj < 2; jj++) {
        acc[mi + ii][nj + jj] = __builtin_amdgcn_mfma_f32_16x16x32_bf16(
            a[ii][0], bb[jj][0], acc[mi + ii][nj + jj], 0, 0, 0);
        acc[mi + ii][nj + jj] = __builtin_amdgcn_mfma_f32_16x16x32_bf16(
            a[ii][1], bb[jj][1], acc[mi + ii][nj + jj], 0, 0, 0);
      }
  };

#define BARX() __builtin_amdgcn_s_barrier()
#define LGKM0() do { asm volatile("s_waitcnt lgkmcnt(0)" ::: "memory"); \
                     __builtin_amdgcn_sched_barrier(0); } while (0)
#define HALF4(BC, DOA, SAB, SAK, DOB, SBB, SBK, VMN)                      \
  do {                                                                    \
    rdA(BC, 0); rdB(BC, 0, b01);                                          \
    if (DOA) stA(SAB, 0, SAK);                                            \
    BARX(); LGKM0();                                                      \
    __builtin_amdgcn_s_setprio(1); mm4(0, b01, 0);                        \
    __builtin_amdgcn_s_setprio(0); BARX();                                \
    rdB(BC, 1, b23);                                                      \
    if (DOA) stA(SAB, 1, SAK);                                            \
    BARX(); LGKM0();                                                      \
    __builtin_amdgcn_s_setprio(1); mm4(0, b23, 2);                        \
    __builtin_amdgcn_s_setprio(0); BARX();                                \
    rdA(BC, 1);                                                           \
    if (DOB) stB(SBB, 0, SBK);                                            \
    BARX(); LGKM0();                                                      \
    __builtin_amdgcn_s_setprio(1); mm4(4, b01, 0);                        \
    __builtin_amdgcn_s_setprio(0); BARX();                                \
    if (DOB) stB(SBB, 1, SBK);                                            \
    BARX();                                                               \
    __builtin_amdgcn_s_setprio(1); mm4(4, b23, 2);                        \
    __builtin_amdgcn_s_setprio(0);                                        \
    asm volatile("s_waitcnt vmcnt(" VMN ")" ::: "memory");                \
    BARX();                                                               \
  } while (0)

  const int nt = nk >> 6;
  // prologue: tile0 (8 loads) + tile1.B (4 loads); vmcnt(4) -> tile0 landed
  stA(0, 0, 0); stA(0, 1, 0);
  stB(0, 0, 0); stB(0, 1, 0);
  stB(1, 0, 1); stB(1, 1, 1);
  asm volatile("s_waitcnt vmcnt(4)" ::: "memory");
  BARX();
  int tt = 0;
  for (; tt + 2 < nt; tt += 2) {
    HALF4(0, 1, 1, tt + 1, 1, 0, tt + 2, "4");
    HALF4(1, 1, 0, tt + 2, 1, 1, tt + 3, "4");
  }
  // tail: tt = nt-2; stage only (nt-1).A, drain fully before last tile
  HALF4(0, 1, 1, tt + 1, 0, 0, 0, "0");
  HALF4(1, 0, 0, 0, 0, 0, 0, "0");
#undef HALF4
#undef LGKM0
#undef BARX
}

// ---------------- FFN1: act bf16 = gelu(h @ W1 + b1), N=4096 K=1024 ---------
__global__ __launch_bounds__(512, 2) void gemm_ffn1(const bf16* __restrict__ A,
                                                    const bf16* __restrict__ BT,
                                                    const float* __restrict__ bias,
                                                    bf16* __restrict__ out,
                                                    int N, int K) {
  extern __shared__ char lds[];
  int t = threadIdx.x;
  int nf = swz8(blockIdx.x, gridDim.x);
  int n0 = (nf & 15) * 256, m0 = (nf >> 4) * 256;
  f32x4 acc[8][4];
  #pragma unroll
  for (int i = 0; i < 8; i++)
    #pragma unroll
    for (int j = 0; j < 4; j++) acc[i][j] = (f32x4){0.f, 0.f, 0.f, 0.f};
  mainloop_256(A, BT, K, K, m0, n0, lds, t, acc);

  int lane = t & 63, wave = t >> 6;
  int l = lane & 15, quad = lane >> 4;
  int wm = (wave >> 2) * 128, wn = (wave & 3) * 64;
  int r4 = quad * 4;
  unsigned short* os = reinterpret_cast<unsigned short*>(out);
  #pragma unroll
  for (int i = 0; i < 8; i++)
    #pragma unroll
    for (int j = 0; j < 4; j++) {
      int col = n0 + wn + j * 16 + l;
      float bval = bias[col];
      #pragma unroll
      for (int r = 0; r < 4; r++) {
        int row = m0 + wm + i * 16 + r4 + r;
        os[(size_t)row * N + col] = f2bf_rne(gelu_fast(acc[i][j][r] + bval));
      }
    }
}

// ------- FFN2 split-K (8-phase) + FUSED cross-z reduce -------
// M=4096 N=1024 K=4096; z in 0..3, each K=1024; grid 256 blocks = 1/CU (all
// co-resident -> spin on per-tile counter is deadlock-free). After gemm:
// write partial, release-fence, bump counter; when all 4 z-blocks of the
// (m,n)-tile are done, each reduces its own 64-row quarter (p0..p3 + x1 +
// bias -> out). Replaces the standalone reduce kernel; the 80MB reduce runs
// on all 256 CUs inside this kernel.
__global__ __launch_bounds__(512, 2) void gemm_ffn2(const bf16* __restrict__ A,
                                                    const bf16* __restrict__ BT,
                                                    unsigned short* __restrict__ p0,
                                                    unsigned short* __restrict__ p1,
                                                    unsigned short* __restrict__ p2,
                                                    unsigned short* __restrict__ p3,
                                                    const float* __restrict__ x1,
                                                    const float* __restrict__ bias,
                                                    float* __restrict__ out,
                                                    int* __restrict__ cnt) {
  extern __shared__ char lds[];
  int t = threadIdx.x;
  int nf = swz8(blockIdx.x, gridDim.x);
  int n0 = (nf & 3) * 256, m0 = ((nf >> 2) & 15) * 256;
  int z = nf >> 6;
  int tid = (m0 >> 8) * 4 + (n0 >> 8);  // 0..63
  f32x4 acc[8][4];
  #pragma unroll
  for (int i = 0; i < 8; i++)
    #pragma unroll
    for (int j = 0; j < 4; j++) acc[i][j] = (f32x4){0.f, 0.f, 0.f, 0.f};
  mainloop_256(A + z * 1024, BT + z * 1024, 4096, 1024, m0, n0, lds, t, acc);

  unsigned short* p = z == 0 ? p0 : (z == 1 ? p1 : (z == 2 ? p2 : p3));
  int lane = t & 63, wave = t >> 6;
  int l = lane & 15, quad = lane >> 4;
  int wm = (wave >> 2) * 128, wn = (wave & 3) * 64;
  int r4 = quad * 4;
  #pragma unroll
  for (int i = 0; i < 8; i++)
    #pragma unroll
    for (int j = 0; j < 4; j++) {
      int col = n0 + wn + j * 16 + l;
      #pragma unroll
      for (int r = 0; r < 4; r++) {
        int row = m0 + wm + i * 16 + r4 + r;
        p[(size_t)row * 1024 + col] = f2bf_rne(acc[i][j][r]);
      }
    }

  // ---- fused reduce: wait for the 3 sibling z-blocks, then do my quarter ---
  __threadfence();
  __syncthreads();
  if (t == 0) {
    atomicAdd(cnt + tid, 1);
    while (atomicAdd(cnt + tid, 0) < 4) __builtin_amdgcn_s_sleep(2);
  }
  __syncthreads();
  __threadfence();
  {
    int col4 = t & 63;
    float4 bv = ((const float4*)bias)[(n0 >> 2) + col4];
    int rbase = m0 + z * 64 + (t >> 6) * 8;
    #pragma unroll
    for (int k = 0; k < 8; k++) {
      size_t base = (size_t)(rbase + k) * 1024 + n0;
      ushort4 a = ((const ushort4*)(p0 + base))[col4];
      ushort4 b = ((const ushort4*)(p1 + base))[col4];
      ushort4 c = ((const ushort4*)(p2 + base))[col4];
      ushort4 d = ((const ushort4*)(p3 + base))[col4];
      float4 xv = ((const float4*)(x1 + base))[col4];
      float4 o;
      o.x = (bf2f(a.x) + bf2f(b.x)) + (bf2f(c.x) + bf2f(d.x)) + xv.x + bv.x;
      o.y = (bf2f(a.y) + bf2f(b.y)) + (bf2f(c.y) + bf2f(d.y)) + xv.y + bv.y;
      o.z = (bf2f(a.z) + bf2f(b.z)) + (bf2f(c.z) + bf2f(d.z)) + xv.z + bv.z;
      o.w = (bf2f(a.w) + bf2f(b.w)) + (bf2f(c.w) + bf2f(d.w)) + xv.w + bv.w;
      ((float4*)(out + base))[col4] = o;
    }
  }
}

// ------------- fused QKV GEMM: N=3072 (q|k|v); v written transposed ----------
__global__ __launch_bounds__(512, 2) void gemm_qkv(const bf16* __restrict__ A,
                                                   const bf16* __restrict__ BT,
                                                   const float* __restrict__ bq,
                                                   const float* __restrict__ bk,
                                                   const float* __restrict__ bv,
                                                   bf16* __restrict__ qb,
                                                   bf16* __restrict__ kb,
                                                   bf16* __restrict__ vt,
                                                   int K) {
  extern __shared__ char lds[];
  int t = threadIdx.x;
  int nf = swz8(blockIdx.x, gridDim.x);
  int n0 = (nf % 12) * 256, m0 = (nf / 12) * 256;
  f32x4 acc[8][4];
  #pragma unroll
  for (int i = 0; i < 8; i++)
    #pragma unroll
    for (int j = 0; j < 4; j++) acc[i][j] = (f32x4){0.f, 0.f, 0.f, 0.f};
  mainloop_256(A, BT, K, K, m0, n0, lds, t, acc);

  int lane = t & 63, wave = t >> 6;
  int l = lane & 15, quad = lane >> 4;
  int wm = (wave >> 2) * 128, wn = (wave & 3) * 64;
  int sect = n0 >> 10;  // 0=q 1=k 2=v (BN=256 divides 1024 sections)
  const float* bias = sect == 0 ? bq : (sect == 1 ? bk : bv);
  int r4 = quad * 4;
  #pragma unroll
  for (int i = 0; i < 8; i++)
    #pragma unroll
    for (int j = 0; j < 4; j++) {
      int col = n0 + wn + j * 16 + l;
      int c1 = col & 1023;
      float bval = bias[c1];
      int row0 = m0 + wm + i * 16 + r4;
      if (sect < 2) {
        bf16* o = sect == 0 ? qb : kb;
        unsigned short* os = reinterpret_cast<unsigned short*>(o);
        #pragma unroll
        for (int r = 0; r < 4; r++)
          os[(size_t)(row0 + r) * 1024 + c1] = f2bf_rne(acc[i][j][r] + bval);
      } else {
        int hh = c1 >> 6, d = c1 & 63;
        int b = row0 >> 11, t0 = row0 & 2047;
        ushort4 pk;
        pk.x = f2bf_rne(acc[i][j][0] + bval);
        pk.y = f2bf_rne(acc[i][j][1] + bval);
        pk.z = f2bf_rne(acc[i][j][2] + bval);
        pk.w = f2bf_rne(acc[i][j][3] + bval);
        *(ushort4*)((unsigned short*)vt + (size_t)((b * 16 + hh) * 64 + d) * 2048 + t0) = pk;
      }
    }
}

// ---------------- MFMA flash attention v8 (v7 + fused ln2) ----------------
// One i-tile per block; 8 waves = 2 groups of 4, each group its own KV
// double-buffer over alternating j-tiles; in-block partial combine. After
// the x1 write, the LAST of the 16 head-blocks for this (b, i-tile) runs
// LayerNorm2 over its 64 completed rows and writes h (device-scope
// counter handshake) -> kills the standalone ln2 kernel; LN work hides
// under still-running attention blocks. LDS 80KB -> 2 blocks/CU.
__global__ __launch_bounds__(512, 4) void attn_mfma(const bf16* __restrict__ qb,
                                                    const bf16* __restrict__ kb,
                                                    const bf16* __restrict__ vt,
                                                    const float* __restrict__ x,
                                                    float* __restrict__ x1,
                                                    const float* __restrict__ ln2g,
                                                    const float* __restrict__ ln2b,
                                                    bf16* __restrict__ hout,
                                                    int* __restrict__ cnt) {
  extern __shared__ char alds[];
  char* KVb = alds;           // 64KB: g*32768 + buf*16384 + (K:0|V:8192) + w4*2048
  char* Pb  = alds + 65536;   // 16KB: wave*2048, row l stride 128B
  int t = threadIdx.x;
  int bh = blockIdx.x;
  int b = bh >> 4, h = bh & 15;
  size_t qk_base = (size_t)b * 2048 * 1024 + (size_t)h * 64;
  size_t vt_base = (size_t)bh * 64 * 2048;
  int lane = t & 63, wave = t >> 6;
  int g = wave >> 2, w4 = wave & 3;
  int l = lane & 15, quad = lane >> 4;
  int sw = l & 7;
  int srow8 = lane >> 3;                       // staging row-in-8 (0..7)
  int scol = ((lane & 7) ^ srow8) * 8;         // swizzled source col (elems)
  const float cs = 0.125f * 1.44269504088896f; // scale * log2(e)
  int it = 31 - blockIdx.y;                    // largest first
  int i0 = it * 64;
  int njt = it + 1;
  int iblk = i0 + w4 * 16;

  // prologue: waves 0-3 stage Q (into P region) + group0 KV tile0;
  // waves 4-7 stage group1 KV tile1 (if it exists)
  if (g == 0) {
    #pragma unroll
    for (int c = 0; c < 2; c++) {
      int rr = w4 * 16 + c * 8 + srow8;
      gl2lds16(kb + qk_base + (size_t)(i0 + rr) * 1024 + scol,
               Pb + w4 * 2048 + c * 1024);
      gl2lds16(qb + qk_base + (size_t)rr * 1024 + scol,
               KVb + w4 * 2048 + c * 1024);
      gl2lds16(vt + vt_base + (size_t)rr * 2048 + scol,
               KVb + 8192 + w4 * 2048 + c * 1024);
    }
  } else if (njt > 1) {
    #pragma unroll
    for (int c = 0; c < 2; c++) {
      int rr = w4 * 16 + c * 8 + srow8;
      gl2lds16(qb + qk_base + (size_t)(64 + rr) * 1024 + scol,
               KVb + 32768 + w4 * 2048 + c * 1024);
      gl2lds16(vt + vt_base + (size_t)rr * 2048 + 64 + scol,
               KVb + 32768 + 8192 + w4 * 2048 + c * 1024);
    }
  }
  __syncthreads();  // drains vmcnt: Q + first tiles visible

  const char* qr = Pb + w4 * 2048 + l * 128;
  bf16x8 qf0 = *(const bf16x8*)(qr + ((quad ^ sw) * 16));
  bf16x8 qf1 = *(const bf16x8*)(qr + (((4 + quad) ^ sw) * 16));
  __syncthreads();  // all waves hold Q in regs; P region may be overlaid now

  float lsum = 0.f;
  f32x4 Oacc[4];
  #pragma unroll
  for (int dt = 0; dt < 4; dt++) Oacc[dt] = (f32x4){0.f, 0.f, 0.f, 0.f};

  char* Pw = Pb + wave * 2048 + l * 128;  // own-wave P row base
  char* KVg = KVb + g * 32768;
  int nstep = (njt + 1) >> 1;
  int buf = 0;
  for (int s = 0; s < nstep; s++) {
    int jt = 2 * s + g;
    // prefetch my group's tile jt+2 into other buffer
    if (jt + 2 < njt) {
      int j1 = (jt + 2) * 64;
      #pragma unroll
      for (int c = 0; c < 2; c++) {
        int rr = w4 * 16 + c * 8 + srow8;
        gl2lds16(qb + qk_base + (size_t)(j1 + rr) * 1024 + scol,
                 KVg + (buf ^ 1) * 16384 + w4 * 2048 + c * 1024);
        gl2lds16(vt + vt_base + (size_t)rr * 2048 + j1 + scol,
                 KVg + (buf ^ 1) * 16384 + 8192 + w4 * 2048 + c * 1024);
      }
    }
    if (jt < njt) {
      int j0v = jt * 64;
      // S^T per nt: A = K rows (m=j), B = Q frag (n=i)
      const bf16* Kb = (const bf16*)(KVg + buf * 16384);
      #pragma unroll
      for (int nt = 0; nt < 4; nt++) {
        int jb = j0v + nt * 16;
        uint2 pk;
        if (jb > iblk + 15) {  // fully masked
          pk.x = 0u; pk.y = 0u;
        } else {
          const bf16* kr = Kb + (nt * 16 + l) * 64;
          bf16x8 kf0 = *(const bf16x8*)(kr + ((quad ^ sw) * 8));
          bf16x8 kf1 = *(const bf16x8*)(kr + (((4 + quad) ^ sw) * 8));
          f32x4 sv = (f32x4){0.f, 0.f, 0.f, 0.f};
          sv = __builtin_amdgcn_mfma_f32_16x16x32_bf16(kf0, qf0, sv, 0, 0, 0);
          sv = __builtin_amdgcn_mfma_f32_16x16x32_bf16(kf1, qf1, sv, 0, 0, 0);
          float p0, p1, p2, p3;
          if (jb + 15 <= iblk) {  // fully unmasked
            p0 = __builtin_amdgcn_exp2f(sv[0] * cs);
            p1 = __builtin_amdgcn_exp2f(sv[1] * cs);
            p2 = __builtin_amdgcn_exp2f(sv[2] * cs);
            p3 = __builtin_amdgcn_exp2f(sv[3] * cs);
          } else {                // diagonal straddle
            int i_ = iblk + l, jbase = jb + quad * 4;
            p0 = (jbase + 0 > i_) ? 0.f : __builtin_amdgcn_exp2f(sv[0] * cs);
            p1 = (jbase + 1 > i_) ? 0.f : __builtin_amdgcn_exp2f(sv[1] * cs);
            p2 = (jbase + 2 > i_) ? 0.f : __builtin_amdgcn_exp2f(sv[2] * cs);
            p3 = (jbase + 3 > i_) ? 0.f : __builtin_amdgcn_exp2f(sv[3] * cs);
          }
          lsum += (p0 + p1) + (p2 + p3);
          union { __hip_bfloat162 h2; unsigned u; } c0u, c1u;
          c0u.h2 = __float22bfloat162_rn(make_float2(p0, p1));
          c1u.h2 = __float22bfloat162_rn(make_float2(p2, p3));
          pk.x = c0u.u; pk.y = c1u.u;
        }
        // P row byte offset: 16B group g16=nt*2+(quad>>1) swizzled by sw
        *(uint2*)(Pw + (((nt * 2 + (quad >> 1)) ^ sw) << 4) + ((quad & 1) << 3)) = pk;
      }
      asm volatile("s_waitcnt lgkmcnt(0)" ::: "memory");  // own-wave P only

      // PV: A = P rows (m=i), B = V rows (n=d)
      bf16x8 ap0 = *(const bf16x8*)(Pw + ((quad ^ sw) << 4));
      bf16x8 ap1 = *(const bf16x8*)(Pw + (((4 + quad) ^ sw) << 4));
      const bf16* Vb = (const bf16*)(KVg + buf * 16384 + 8192);
      #pragma unroll
      for (int dt = 0; dt < 4; dt++) {
        const bf16* vr = Vb + (dt * 16 + l) * 64;
        bf16x8 bv0 = *(const bf16x8*)(vr + ((quad ^ sw) * 8));
        bf16x8 bv1 = *(const bf16x8*)(vr + (((4 + quad) ^ sw) * 8));
        Oacc[dt] = __builtin_amdgcn_mfma_f32_16x16x32_bf16(ap0, bv0, Oacc[dt], 0, 0, 0);
        Oacc[dt] = __builtin_amdgcn_mfma_f32_16x16x32_bf16(ap1, bv1, Oacc[dt], 0, 0, 0);
      }
    }
    __syncthreads();  // drains prefetch (vmcnt) + group done with buf
    buf ^= 1;
  }

  // in-block combine: group1 -> LDS (KV region now free) -> group0 adds
  float* F = (float*)KVb;
  int fbase = w4 * 1088;
  if (g == 1) {
    #pragma unroll
    for (int dt = 0; dt < 4; dt++)
      #pragma unroll
      for (int r = 0; r < 4; r++)
        F[fbase + (dt * 4 + r) * 64 + lane] = Oacc[dt][r];
    F[fbase + 1024 + lane] = lsum;
  }
  __syncthreads();
  if (g == 0) {
    #pragma unroll
    for (int dt = 0; dt < 4; dt++)
      #pragma unroll
      for (int r = 0; r < 4; r++)
        Oacc[dt][r] += F[fbase + (dt * 4 + r) * 64 + lane];
    lsum += F[fbase + 1024 + lane];
    // denominator: sum over quads (each lane's lsum is i=l partial)
    lsum += __shfl_xor(lsum, 16);
    lsum += __shfl_xor(lsum, 32);
    #pragma unroll
    for (int r = 0; r < 4; r++) {
      float lv = __shfl(lsum, quad * 4 + r);
      float inv = 1.0f / lv;
      int row = iblk + quad * 4 + r;
      size_t gi = qk_base + (size_t)row * 1024;
      #pragma unroll
      for (int dt = 0; dt < 4; dt++) {
        int d = dt * 16 + l;
        x1[gi + d] = x[gi + d] + Oacc[dt][r] * inv;
      }
    }
  }

  // ---- fused ln2: last head-block for (b, i-tile) normalizes its 64 rows ---
  __threadfence();
  __syncthreads();
  int* scnt = (int*)(alds + 18432);  // free LDS (beyond F region)
  if (t == 0) *scnt = atomicAdd(cnt + (b * 32 + (int)blockIdx.y), 1);
  __syncthreads();
  if (*scnt == 15) {
    __threadfence();  // acquire: other head-blocks' x1 writes visible
    int rowbase = b * 2048 + i0 + wave * 8;
    const float4* gv4 = (const float4*)ln2g;
    const float4* bv4 = (const float4*)ln2b;
    for (int rr = 0; rr < 8; rr++) {
      int row = rowbase + rr;
      const float4* xr = (const float4*)(x1 + (size_t)row * 1024);
      float4 v[4];
      float s = 0.f, sq = 0.f;
      #pragma unroll
      for (int p = 0; p < 4; p++) {
        v[p] = xr[p * 64 + lane];
        s += (v[p].x + v[p].y) + (v[p].z + v[p].w);
        sq += (v[p].x * v[p].x + v[p].y * v[p].y) + (v[p].z * v[p].z + v[p].w * v[p].w);
      }
      #pragma unroll
      for (int m = 1; m < 64; m <<= 1) { s += __shfl_xor(s, m); sq += __shfl_xor(sq, m); }
      float mean = s * (1.0f / 1024.0f);
      float var = sq * (1.0f / 1024.0f) - mean * mean;
      float rs = rsqrtf(var + 1e-3f);
      ushort4* hr = (ushort4*)(hout + (size_t)row * 1024);
      #pragma unroll
      for (int p = 0; p < 4; p++) {
        float4 gv = gv4[p * 64 + lane];
        float4 bv = bv4[p * 64 + lane];
        ushort4 o;
        o.x = f2bf_rne((v[p].x - mean) * rs * gv.x + bv.x);
        o.y = f2bf_rne((v[p].y - mean) * rs * gv.y + bv.y);
        o.z = f2bf_rne((v[p].z - mean) * rs * gv.z + bv.z);
        o.w = f2bf_rne((v[p].w - mean) * rs * gv.w + bv.w);
        hr[p * 64 + lane] = o;
      }
    }
  }
}

extern "C" void kernel_launch(void* const* d_in, const int* in_sizes, int n_in,
                              void* d_out, int out_size, void* d_ws, size_t ws_size,
                              hipStream_t stream) {
  const float* x    = (const float*)d_in[0];
  const float* ln1g = (const float*)d_in[1];
  const float* ln1b = (const float*)d_in[2];
  const float* Wq   = (const float*)d_in[3];
  const float* bq   = (const float*)d_in[4];
  const float* Wk   = (const float*)d_in[5];
  const float* bk   = (const float*)d_in[6];
  const float* Wv   = (const float*)d_in[7];
  const float* bv   = (const float*)d_in[8];
  const float* ln2g = (const float*)d_in[9];
  const float* ln2b = (const float*)d_in[10];
  const float* W1   = (const float*)d_in[11];
  const float* b1   = (const float*)d_in[12];
  const float* W2   = (const float*)d_in[13];
  const float* b2   = (const float*)d_in[14];

  char* ws = (char*)d_ws;
  float* x1  = (float*)(ws + 0);            // 16 MB f32 [4096][1024]
  bf16* h    = (bf16*)(ws + 16777216);      //  8 MB bf16 [4096][1024]  (reused: FFN2 partial 3)
  bf16* WqkT = (bf16*)(ws + 25165824);      //  6 MB bf16 [3072][1024] (q|k|v)
  bf16* W1T  = (bf16*)(ws + 31457280);      //  8 MB [4096][1024]
  bf16* W2T  = (bf16*)(ws + 39845888);      //  8 MB [1024][4096]
  bf16* qb   = (bf16*)(ws + 48234496);      //  8 MB [4096][1024]  (reused: FFN2 partial 0)
  bf16* kb   = (bf16*)(ws + 56623104);      //  8 MB [4096][1024]  (reused: FFN2 partial 1)
  bf16* vt   = (bf16*)(ws + 65011712);      //  8 MB [b,h,d,t] = [2048][2048] (reused: FFN2 partial 2)
  bf16* act  = (bf16*)(ws + 73400320);      // 32 MB [4096][4096]
  int*  cnt  = (int*)(ws + 106954752);      // 128 ints: [0..63] attn-ln2, [64..127] ffn2

  static bool s_attr_done = false;
  if (!s_attr_done) {
    hipFuncSetAttribute(reinterpret_cast<const void*>(gemm_qkv),
                        hipFuncAttributeMaxDynamicSharedMemorySize, 131072);
    hipFuncSetAttribute(reinterpret_cast<const void*>(gemm_ffn1),
                        hipFuncAttributeMaxDynamicSharedMemorySize, 131072);
    hipFuncSetAttribute(reinterpret_cast<const void*>(gemm_ffn2),
                        hipFuncAttributeMaxDynamicSharedMemorySize, 131072);
    hipFuncSetAttribute(reinterpret_cast<const void*>(attn_mfma),
                        hipFuncAttributeMaxDynamicSharedMemorySize, 81920);
    s_attr_done = true;
  }

  prep_fused<<<15360, 256, 0, stream>>>(x, ln1g, ln1b, h,
                                        Wq, Wk, Wv, W1, W2, WqkT, W1T, W2T, cnt);
  gemm_qkv<<<192, 512, 131072, stream>>>(h, WqkT, bq, bk, bv, qb, kb, vt, 1024);
  attn_mfma<<<dim3(32, 32), 512, 81920, stream>>>(qb, kb, vt, x, x1,
                                                  ln2g, ln2b, h, cnt);
  gemm_ffn1<<<256, 512, 131072, stream>>>(h, W1T, b1, act, 4096, 1024);
  gemm_ffn2<<<256, 512, 131072, stream>>>(act, W2T,
      (unsigned short*)qb, (unsigned short*)kb, (unsigned short*)vt, (unsigned short*)h,
      x1, b2, (float*)d_out, cnt + 64);
}

// Round 8
// 288.753 us; speedup vs baseline: 2.4074x; 2.4074x over previous
//
#include <hip/hip_runtime.h>
#include <hip/hip_bf16.h>
#include <math.h>

typedef __hip_bfloat16 bf16;
typedef __attribute__((ext_vector_type(8))) short bf16x8;
typedef __attribute__((ext_vector_type(4))) float f32x4;

__device__ __forceinline__ unsigned short f2bf_rne(float f) {
  unsigned u = __float_as_uint(f);
  u += 0x7fffu + ((u >> 16) & 1u);
  return (unsigned short)(u >> 16);
}
__device__ __forceinline__ float bf2f(unsigned short s) {
  return __uint_as_float(((unsigned)s) << 16);
}

// fast tanh-form GELU: max |diff| vs exact erf-GELU ~1e-3
__device__ __forceinline__ float gelu_fast(float v) {
  float u = v * (0.7978845608f + 0.0356774081f * v * v);
  float t = __builtin_amdgcn_exp2f(u * 2.8853900818f);
  float r = __builtin_amdgcn_rcpf(t + 1.0f);
  return v - v * r;
}

#define GLOBAL_AS __attribute__((address_space(1)))
#define LDS_AS __attribute__((address_space(3)))
__device__ __forceinline__ void gl2lds16(const void* g, void* l) {
  __builtin_amdgcn_global_load_lds((const GLOBAL_AS void*)g, (LDS_AS void*)l, 16, 0, 0);
}

// T1: XCD-chunked bijective swizzle (nwg % 8 == 0).
__device__ __forceinline__ int swz8(int f, int nwg) {
  return (f & 7) * (nwg >> 3) + (f >> 3);
}

// ---------------- LayerNorm body: x f32 [row][1024] -> h bf16 ----------------
__device__ __forceinline__ void ln_body(const float* __restrict__ x,
                                        const float* __restrict__ g,
                                        const float* __restrict__ b,
                                        bf16* __restrict__ h, int row, int t) {
  const float4 xv = ((const float4*)(x + (size_t)row * 1024))[t];
  float s = xv.x + xv.y + xv.z + xv.w;
  float sq = xv.x * xv.x + xv.y * xv.y + xv.z * xv.z + xv.w * xv.w;
  #pragma unroll
  for (int m = 1; m < 64; m <<= 1) { s += __shfl_xor(s, m); sq += __shfl_xor(sq, m); }
  __shared__ float ps[4], pq[4];
  if ((t & 63) == 0) { ps[t >> 6] = s; pq[t >> 6] = sq; }
  __syncthreads();
  s = ps[0] + ps[1] + ps[2] + ps[3];
  sq = pq[0] + pq[1] + pq[2] + pq[3];
  float mean = s * (1.0f / 1024.0f);
  float var = sq * (1.0f / 1024.0f) - mean * mean;
  float rs = rsqrtf(var + 1e-3f);
  float4 gv = ((const float4*)g)[t];
  float4 bv = ((const float4*)b)[t];
  ushort4 o;
  o.x = f2bf_rne((xv.x - mean) * rs * gv.x + bv.x);
  o.y = f2bf_rne((xv.y - mean) * rs * gv.y + bv.y);
  o.z = f2bf_rne((xv.z - mean) * rs * gv.z + bv.z);
  o.w = f2bf_rne((xv.w - mean) * rs * gv.w + bv.w);
  ((ushort4*)(h + (size_t)row * 1024))[t] = o;
}

__global__ __launch_bounds__(256) void ln_kernel(const float* __restrict__ x,
                                                 const float* __restrict__ g,
                                                 const float* __restrict__ b,
                                                 bf16* __restrict__ h) {
  ln_body(x, g, b, h, blockIdx.x, threadIdx.x);
}

// ------------- merged transpose + f32->bf16 for all 5 weights -------------
__device__ __forceinline__ void tr_tile(const float* __restrict__ W, bf16* __restrict__ WT,
                                        int R, int Cc, int bx, int by, int t) {
  __shared__ float tile[32][33];
  int tx = t & 31, ty = t >> 5;
  #pragma unroll
  for (int k = 0; k < 4; k++) {
    int rr = ty + k * 8;
    tile[rr][tx] = W[(size_t)(by + rr) * Cc + bx + tx];
  }
  __syncthreads();
  unsigned short* out = reinterpret_cast<unsigned short*>(WT);
  #pragma unroll
  for (int k = 0; k < 4; k++) {
    int rr = ty + k * 8;
    out[(size_t)(bx + rr) * R + by + tx] = f2bf_rne(tile[tx][rr]);
  }
}

// -------- fused prep: ln1 (blocks 0..4095) + weight transposes (rest) -------
__global__ __launch_bounds__(256) void prep_fused(const float* __restrict__ x,
                                                  const float* __restrict__ ln1g,
                                                  const float* __restrict__ ln1b,
                                                  bf16* __restrict__ h,
                                                  const float* __restrict__ Wq,
                                                  const float* __restrict__ Wk,
                                                  const float* __restrict__ Wv,
                                                  const float* __restrict__ W1,
                                                  const float* __restrict__ W2,
                                                  bf16* __restrict__ WqkT,
                                                  bf16* __restrict__ W1T,
                                                  bf16* __restrict__ W2T) {
  int id = blockIdx.x, t = threadIdx.x;
  if (id < 4096) { ln_body(x, ln1g, ln1b, h, id, t); return; }
  id -= 4096;
  if (id < 3072) {
    int sect = id >> 10, r = id & 1023;
    const float* W = sect == 0 ? Wq : (sect == 1 ? Wk : Wv);
    bf16* WT = WqkT + (size_t)sect * 1048576;
    tr_tile(W, WT, 1024, 1024, (r & 31) * 32, (r >> 5) * 32, t);
  } else if (id < 7168) {
    int r = id - 3072;
    tr_tile(W1, W1T, 1024, 4096, (r & 127) * 32, (r >> 7) * 32, t);
  } else {
    int r = id - 7168;
    tr_tile(W2, W2T, 4096, 1024, (r & 31) * 32, (r >> 5) * 32, t);
  }
}

// ============ 256x256 8-phase GEMM mainloop (T2+T3+T4+T5) ============
// (unchanged; see round-1 comment block for schedule derivation)
__device__ __forceinline__ void mainloop_256(const bf16* __restrict__ A,
                                             const bf16* __restrict__ BT,
                                             int lda, int nk, int m0, int n0,
                                             char* ldsb, int t,
                                             f32x4 (&acc)[8][4]) {
  const int lane = t & 63, wave = t >> 6;
  const int l = lane & 15, quad = lane >> 4;
  const int wm = (wave >> 2) * 128, wn = (wave & 3) * 64;
  const int srow = wave * 8 + (lane >> 3);          // row within 64-row round
  const int scol = ((lane & 7) ^ (lane >> 3)) * 8;  // pre-swizzled global col
  const int grp0 = (quad ^ (l & 7)) * 16;           // swizzled 16B group, k-slice 0
  const int grp1 = ((4 + quad) ^ (l & 7)) * 16;     // k-slice 1

  bf16x8 a[4][2], b01[2][2], b23[2][2];

  auto stA = [&](int buf, int half, int kt) {
    const bf16* s = A + (size_t)(m0 + half * 128 + srow) * lda + kt * 64 + scol;
    char* d = ldsb + buf * 65536 + half * 16384 + wave * 1024;
    gl2lds16(s, d);
    gl2lds16(s + (size_t)64 * lda, d + 8192);
  };
  auto stB = [&](int buf, int half, int kt) {
    const bf16* s = BT + (size_t)(n0 + half * 128 + srow) * lda + kt * 64 + scol;
    char* d = ldsb + buf * 65536 + 32768 + half * 16384 + wave * 1024;
    gl2lds16(s, d);
    gl2lds16(s + (size_t)64 * lda, d + 8192);
  };
  auto rdA = [&](int buf, int mh) {
    const char* base = ldsb + buf * 65536 + (wm + mh * 64 + l) * 128;
    #pragma unroll
    for (int ii = 0; ii < 4; ii++) {
      a[ii][0] = *(const bf16x8*)(base + ii * 2048 + grp0);
      a[ii][1] = *(const bf16x8*)(base + ii * 2048 + grp1);
    }
  };
  auto rdB = [&](int buf, int nh, bf16x8 (&bb)[2][2]) {
    const char* base = ldsb + buf * 65536 + 32768 + (wn + nh * 32 + l) * 128;
    #pragma unroll
    for (int jj = 0; jj < 2; jj++) {
      bb[jj][0] = *(const bf16x8*)(base + jj * 2048 + grp0);
      bb[jj][1] = *(const bf16x8*)(base + jj * 2048 + grp1);
    }
  };
  auto mm4 = [&](int mi, bf16x8 (&bb)[2][2], int nj) {
    #pragma unroll
    for (int ii = 0; ii < 4; ii++)
      #pragma unroll
      for (int jj = 0; jj < 2; jj++) {
        acc[mi + ii][nj + jj] = __builtin_amdgcn_mfma_f32_16x16x32_bf16(
            a[ii][0], bb[jj][0], acc[mi + ii][nj + jj], 0, 0, 0);
        acc[mi + ii][nj + jj] = __builtin_amdgcn_mfma_f32_16x16x32_bf16(
            a[ii][1], bb[jj][1], acc[mi + ii][nj + jj], 0, 0, 0);
      }
  };

#define BARX() __builtin_amdgcn_s_barrier()
#define LGKM0() do { asm volatile("s_waitcnt lgkmcnt(0)" ::: "memory"); \
                     __builtin_amdgcn_sched_barrier(0); } while (0)
#define HALF4(BC, DOA, SAB, SAK, DOB, SBB, SBK, VMN)                      \
  do {                                                                    \
    rdA(BC, 0); rdB(BC, 0, b01);                                          \
    if (DOA) stA(SAB, 0, SAK);                                            \
    BARX(); LGKM0();                                                      \
    __builtin_amdgcn_s_setprio(1); mm4(0, b01, 0);                        \
    __builtin_amdgcn_s_setprio(0); BARX();                                \
    rdB(BC, 1, b23);                                                      \
    if (DOA) stA(SAB, 1, SAK);                                            \
    BARX(); LGKM0();                                                      \
    __builtin_amdgcn_s_setprio(1); mm4(0, b23, 2);                        \
    __builtin_amdgcn_s_setprio(0); BARX();                                \
    rdA(BC, 1);                                                           \
    if (DOB) stB(SBB, 0, SBK);                                            \
    BARX(); LGKM0();                                                      \
    __builtin_amdgcn_s_setprio(1); mm4(4, b01, 0);                        \
    __builtin_amdgcn_s_setprio(0); BARX();                                \
    if (DOB) stB(SBB, 1, SBK);                                            \
    BARX();                                                               \
    __builtin_amdgcn_s_setprio(1); mm4(4, b23, 2);                        \
    __builtin_amdgcn_s_setprio(0);                                        \
    asm volatile("s_waitcnt vmcnt(" VMN ")" ::: "memory");                \
    BARX();                                                               \
  } while (0)

  const int nt = nk >> 6;
  // prologue: tile0 (8 loads) + tile1.B (4 loads); vmcnt(4) -> tile0 landed
  stA(0, 0, 0); stA(0, 1, 0);
  stB(0, 0, 0); stB(0, 1, 0);
  stB(1, 0, 1); stB(1, 1, 1);
  asm volatile("s_waitcnt vmcnt(4)" ::: "memory");
  BARX();
  int tt = 0;
  for (; tt + 2 < nt; tt += 2) {
    HALF4(0, 1, 1, tt + 1, 1, 0, tt + 2, "4");
    HALF4(1, 1, 0, tt + 2, 1, 1, tt + 3, "4");
  }
  // tail: tt = nt-2; stage only (nt-1).A, drain fully before last tile
  HALF4(0, 1, 1, tt + 1, 0, 0, 0, "0");
  HALF4(1, 0, 0, 0, 0, 0, 0, "0");
#undef HALF4
#undef LGKM0
#undef BARX
}

// ---------------- FFN1: act bf16 = gelu(h @ W1 + b1), N=4096 K=1024 ---------
__global__ __launch_bounds__(512, 2) void gemm_ffn1(const bf16* __restrict__ A,
                                                    const bf16* __restrict__ BT,
                                                    const float* __restrict__ bias,
                                                    bf16* __restrict__ out,
                                                    int N, int K) {
  extern __shared__ char lds[];
  int t = threadIdx.x;
  int nf = swz8(blockIdx.x, gridDim.x);
  int n0 = (nf & 15) * 256, m0 = (nf >> 4) * 256;
  f32x4 acc[8][4];
  #pragma unroll
  for (int i = 0; i < 8; i++)
    #pragma unroll
    for (int j = 0; j < 4; j++) acc[i][j] = (f32x4){0.f, 0.f, 0.f, 0.f};
  mainloop_256(A, BT, K, K, m0, n0, lds, t, acc);

  int lane = t & 63, wave = t >> 6;
  int l = lane & 15, quad = lane >> 4;
  int wm = (wave >> 2) * 128, wn = (wave & 3) * 64;
  int r4 = quad * 4;
  unsigned short* os = reinterpret_cast<unsigned short*>(out);
  #pragma unroll
  for (int i = 0; i < 8; i++)
    #pragma unroll
    for (int j = 0; j < 4; j++) {
      int col = n0 + wn + j * 16 + l;
      float bval = bias[col];
      #pragma unroll
      for (int r = 0; r < 4; r++) {
        int row = m0 + wm + i * 16 + r4 + r;
        os[(size_t)row * N + col] = f2bf_rne(gelu_fast(acc[i][j][r] + bval));
      }
    }
}

// ------- FFN2 split-K (8-phase): partial[z] bf16 = act[:,z] @ W2T[:,z] ------
// 1-D grid 256 (= 4 nx x 16 my x 4 z), T1 swizzle. Separate reduce kernel
// (round-7 fused spin/fence version was 10x slower: device-scope sync
// poisons latency-critical kernels).
__global__ __launch_bounds__(512, 2) void gemm_ffn2(const bf16* __restrict__ A,
                                                    const bf16* __restrict__ BT,
                                                    unsigned short* __restrict__ p0,
                                                    unsigned short* __restrict__ p1,
                                                    unsigned short* __restrict__ p2,
                                                    unsigned short* __restrict__ p3) {
  extern __shared__ char lds[];
  int t = threadIdx.x;
  int nf = swz8(blockIdx.x, gridDim.x);
  int n0 = (nf & 3) * 256, m0 = ((nf >> 2) & 15) * 256;
  int z = nf >> 6;
  f32x4 acc[8][4];
  #pragma unroll
  for (int i = 0; i < 8; i++)
    #pragma unroll
    for (int j = 0; j < 4; j++) acc[i][j] = (f32x4){0.f, 0.f, 0.f, 0.f};
  mainloop_256(A + z * 1024, BT + z * 1024, 4096, 1024, m0, n0, lds, t, acc);

  unsigned short* p = z == 0 ? p0 : (z == 1 ? p1 : (z == 2 ? p2 : p3));
  int lane = t & 63, wave = t >> 6;
  int l = lane & 15, quad = lane >> 4;
  int wm = (wave >> 2) * 128, wn = (wave & 3) * 64;
  int r4 = quad * 4;
  #pragma unroll
  for (int i = 0; i < 8; i++)
    #pragma unroll
    for (int j = 0; j < 4; j++) {
      int col = n0 + wn + j * 16 + l;
      #pragma unroll
      for (int r = 0; r < 4; r++) {
        int row = m0 + wm + i * 16 + r4 + r;
        p[(size_t)row * 1024 + col] = f2bf_rne(acc[i][j][r]);
      }
    }
}

// -------- FFN2 reduce: out f32 = p0 + p1 + p2 + p3 + bias + x1 --------
__global__ __launch_bounds__(256) void reduce_ffn2(const unsigned short* __restrict__ p0,
                                                   const unsigned short* __restrict__ p1,
                                                   const unsigned short* __restrict__ p2,
                                                   const unsigned short* __restrict__ p3,
                                                   const float* __restrict__ x1,
                                                   const float* __restrict__ bias,
                                                   float* __restrict__ out) {
  int row = blockIdx.x, t = threadIdx.x;
  size_t base = (size_t)row * 1024;
  ushort4 a = ((const ushort4*)(p0 + base))[t];
  ushort4 b = ((const ushort4*)(p1 + base))[t];
  ushort4 c = ((const ushort4*)(p2 + base))[t];
  ushort4 d = ((const ushort4*)(p3 + base))[t];
  float4 xv = ((const float4*)(x1 + base))[t];
  float4 bv = ((const float4*)bias)[t];
  float4 o;
  o.x = (bf2f(a.x) + bf2f(b.x)) + (bf2f(c.x) + bf2f(d.x)) + xv.x + bv.x;
  o.y = (bf2f(a.y) + bf2f(b.y)) + (bf2f(c.y) + bf2f(d.y)) + xv.y + bv.y;
  o.z = (bf2f(a.z) + bf2f(b.z)) + (bf2f(c.z) + bf2f(d.z)) + xv.z + bv.z;
  o.w = (bf2f(a.w) + bf2f(b.w)) + (bf2f(c.w) + bf2f(d.w)) + xv.w + bv.w;
  ((float4*)(out + base))[t] = o;
}

// ------------- fused QKV GEMM: N=3072 (q|k|v); v written transposed ----------
__global__ __launch_bounds__(512, 2) void gemm_qkv(const bf16* __restrict__ A,
                                                   const bf16* __restrict__ BT,
                                                   const float* __restrict__ bq,
                                                   const float* __restrict__ bk,
                                                   const float* __restrict__ bv,
                                                   bf16* __restrict__ qb,
                                                   bf16* __restrict__ kb,
                                                   bf16* __restrict__ vt,
                                                   int K) {
  extern __shared__ char lds[];
  int t = threadIdx.x;
  int nf = swz8(blockIdx.x, gridDim.x);
  int n0 = (nf % 12) * 256, m0 = (nf / 12) * 256;
  f32x4 acc[8][4];
  #pragma unroll
  for (int i = 0; i < 8; i++)
    #pragma unroll
    for (int j = 0; j < 4; j++) acc[i][j] = (f32x4){0.f, 0.f, 0.f, 0.f};
  mainloop_256(A, BT, K, K, m0, n0, lds, t, acc);

  int lane = t & 63, wave = t >> 6;
  int l = lane & 15, quad = lane >> 4;
  int wm = (wave >> 2) * 128, wn = (wave & 3) * 64;
  int sect = n0 >> 10;  // 0=q 1=k 2=v (BN=256 divides 1024 sections)
  const float* bias = sect == 0 ? bq : (sect == 1 ? bk : bv);
  int r4 = quad * 4;
  #pragma unroll
  for (int i = 0; i < 8; i++)
    #pragma unroll
    for (int j = 0; j < 4; j++) {
      int col = n0 + wn + j * 16 + l;
      int c1 = col & 1023;
      float bval = bias[c1];
      int row0 = m0 + wm + i * 16 + r4;
      if (sect < 2) {
        bf16* o = sect == 0 ? qb : kb;
        unsigned short* os = reinterpret_cast<unsigned short*>(o);
        #pragma unroll
        for (int r = 0; r < 4; r++)
          os[(size_t)(row0 + r) * 1024 + c1] = f2bf_rne(acc[i][j][r] + bval);
      } else {
        int hh = c1 >> 6, d = c1 & 63;
        int b = row0 >> 11, t0 = row0 & 2047;
        ushort4 pk;
        pk.x = f2bf_rne(acc[i][j][0] + bval);
        pk.y = f2bf_rne(acc[i][j][1] + bval);
        pk.z = f2bf_rne(acc[i][j][2] + bval);
        pk.w = f2bf_rne(acc[i][j][3] + bval);
        *(ushort4*)((unsigned short*)vt + (size_t)((b * 16 + hh) * 64 + d) * 2048 + t0) = pk;
      }
    }
}

// ---------------- MFMA flash attention v7 + XCD-chunked bh mapping ----------
// One i-tile per block; 8 waves = 2 groups of 4, each group its own KV
// double-buffer over alternating j-tiles; in-block partial combine.
// 1-D grid 1024 with T1 chunking: each XCD gets 4 heads (2MB K/V, fits its
// 4MB L2); within a chunk, largest i-tiles dispatch first across the 4 bh.
// No device-scope fences/atomics (round-7 lesson). LDS 80KB -> 2 blocks/CU.
__global__ __launch_bounds__(512, 4) void attn_mfma(const bf16* __restrict__ qb,
                                                    const bf16* __restrict__ kb,
                                                    const bf16* __restrict__ vt,
                                                    const float* __restrict__ x,
                                                    float* __restrict__ x1) {
  extern __shared__ char alds[];
  char* KVb = alds;           // 64KB: g*32768 + buf*16384 + (K:0|V:8192) + w4*2048
  char* Pb  = alds + 65536;   // 16KB: wave*2048, row l stride 128B
  int t = threadIdx.x;
  int nf = swz8(blockIdx.x, 1024);
  int chunk = nf >> 7, local = nf & 127;
  int y = local >> 2;                 // 0..31, ascending = largest-first
  int bh = chunk * 4 + (local & 3);   // 4 heads per XCD chunk
  int b = bh >> 4, h = bh & 15;
  size_t qk_base = (size_t)b * 2048 * 1024 + (size_t)h * 64;
  size_t vt_base = (size_t)bh * 64 * 2048;
  int lane = t & 63, wave = t >> 6;
  int g = wave >> 2, w4 = wave & 3;
  int l = lane & 15, quad = lane >> 4;
  int sw = l & 7;
  int srow8 = lane >> 3;                       // staging row-in-8 (0..7)
  int scol = ((lane & 7) ^ srow8) * 8;         // swizzled source col (elems)
  const float cs = 0.125f * 1.44269504088896f; // scale * log2(e)
  int it = 31 - y;                             // largest first
  int i0 = it * 64;
  int njt = it + 1;
  int iblk = i0 + w4 * 16;

  // prologue: waves 0-3 stage Q (into P region) + group0 KV tile0;
  // waves 4-7 stage group1 KV tile1 (if it exists)
  if (g == 0) {
    #pragma unroll
    for (int c = 0; c < 2; c++) {
      int rr = w4 * 16 + c * 8 + srow8;
      gl2lds16(kb + qk_base + (size_t)(i0 + rr) * 1024 + scol,
               Pb + w4 * 2048 + c * 1024);
      gl2lds16(qb + qk_base + (size_t)rr * 1024 + scol,
               KVb + w4 * 2048 + c * 1024);
      gl2lds16(vt + vt_base + (size_t)rr * 2048 + scol,
               KVb + 8192 + w4 * 2048 + c * 1024);
    }
  } else if (njt > 1) {
    #pragma unroll
    for (int c = 0; c < 2; c++) {
      int rr = w4 * 16 + c * 8 + srow8;
      gl2lds16(qb + qk_base + (size_t)(64 + rr) * 1024 + scol,
               KVb + 32768 + w4 * 2048 + c * 1024);
      gl2lds16(vt + vt_base + (size_t)rr * 2048 + 64 + scol,
               KVb + 32768 + 8192 + w4 * 2048 + c * 1024);
    }
  }
  __syncthreads();  // drains vmcnt: Q + first tiles visible

  const char* qr = Pb + w4 * 2048 + l * 128;
  bf16x8 qf0 = *(const bf16x8*)(qr + ((quad ^ sw) * 16));
  bf16x8 qf1 = *(const bf16x8*)(qr + (((4 + quad) ^ sw) * 16));
  __syncthreads();  // all waves hold Q in regs; P region may be overlaid now

  float lsum = 0.f;
  f32x4 Oacc[4];
  #pragma unroll
  for (int dt = 0; dt < 4; dt++) Oacc[dt] = (f32x4){0.f, 0.f, 0.f, 0.f};

  char* Pw = Pb + wave * 2048 + l * 128;  // own-wave P row base
  char* KVg = KVb + g * 32768;
  int nstep = (njt + 1) >> 1;
  int buf = 0;
  for (int s = 0; s < nstep; s++) {
    int jt = 2 * s + g;
    // prefetch my group's tile jt+2 into other buffer
    if (jt + 2 < njt) {
      int j1 = (jt + 2) * 64;
      #pragma unroll
      for (int c = 0; c < 2; c++) {
        int rr = w4 * 16 + c * 8 + srow8;
        gl2lds16(qb + qk_base + (size_t)(j1 + rr) * 1024 + scol,
                 KVg + (buf ^ 1) * 16384 + w4 * 2048 + c * 1024);
        gl2lds16(vt + vt_base + (size_t)rr * 2048 + j1 + scol,
                 KVg + (buf ^ 1) * 16384 + 8192 + w4 * 2048 + c * 1024);
      }
    }
    if (jt < njt) {
      int j0v = jt * 64;
      // S^T per nt: A = K rows (m=j), B = Q frag (n=i)
      const bf16* Kb = (const bf16*)(KVg + buf * 16384);
      #pragma unroll
      for (int nt = 0; nt < 4; nt++) {
        int jb = j0v + nt * 16;
        uint2 pk;
        if (jb > iblk + 15) {  // fully masked
          pk.x = 0u; pk.y = 0u;
        } else {
          const bf16* kr = Kb + (nt * 16 + l) * 64;
          bf16x8 kf0 = *(const bf16x8*)(kr + ((quad ^ sw) * 8));
          bf16x8 kf1 = *(const bf16x8*)(kr + (((4 + quad) ^ sw) * 8));
          f32x4 sv = (f32x4){0.f, 0.f, 0.f, 0.f};
          sv = __builtin_amdgcn_mfma_f32_16x16x32_bf16(kf0, qf0, sv, 0, 0, 0);
          sv = __builtin_amdgcn_mfma_f32_16x16x32_bf16(kf1, qf1, sv, 0, 0, 0);
          float p0, p1, p2, p3;
          if (jb + 15 <= iblk) {  // fully unmasked
            p0 = __builtin_amdgcn_exp2f(sv[0] * cs);
            p1 = __builtin_amdgcn_exp2f(sv[1] * cs);
            p2 = __builtin_amdgcn_exp2f(sv[2] * cs);
            p3 = __builtin_amdgcn_exp2f(sv[3] * cs);
          } else {                // diagonal straddle
            int i_ = iblk + l, jbase = jb + quad * 4;
            p0 = (jbase + 0 > i_) ? 0.f : __builtin_amdgcn_exp2f(sv[0] * cs);
            p1 = (jbase + 1 > i_) ? 0.f : __builtin_amdgcn_exp2f(sv[1] * cs);
            p2 = (jbase + 2 > i_) ? 0.f : __builtin_amdgcn_exp2f(sv[2] * cs);
            p3 = (jbase + 3 > i_) ? 0.f : __builtin_amdgcn_exp2f(sv[3] * cs);
          }
          lsum += (p0 + p1) + (p2 + p3);
          union { __hip_bfloat162 h2; unsigned u; } c0u, c1u;
          c0u.h2 = __float22bfloat162_rn(make_float2(p0, p1));
          c1u.h2 = __float22bfloat162_rn(make_float2(p2, p3));
          pk.x = c0u.u; pk.y = c1u.u;
        }
        // P row byte offset: 16B group g16=nt*2+(quad>>1) swizzled by sw
        *(uint2*)(Pw + (((nt * 2 + (quad >> 1)) ^ sw) << 4) + ((quad & 1) << 3)) = pk;
      }
      asm volatile("s_waitcnt lgkmcnt(0)" ::: "memory");  // own-wave P only

      // PV: A = P rows (m=i), B = V rows (n=d)
      bf16x8 ap0 = *(const bf16x8*)(Pw + ((quad ^ sw) << 4));
      bf16x8 ap1 = *(const bf16x8*)(Pw + (((4 + quad) ^ sw) << 4));
      const bf16* Vb = (const bf16*)(KVg + buf * 16384 + 8192);
      #pragma unroll
      for (int dt = 0; dt < 4; dt++) {
        const bf16* vr = Vb + (dt * 16 + l) * 64;
        bf16x8 bv0 = *(const bf16x8*)(vr + ((quad ^ sw) * 8));
        bf16x8 bv1 = *(const bf16x8*)(vr + (((4 + quad) ^ sw) * 8));
        Oacc[dt] = __builtin_amdgcn_mfma_f32_16x16x32_bf16(ap0, bv0, Oacc[dt], 0, 0, 0);
        Oacc[dt] = __builtin_amdgcn_mfma_f32_16x16x32_bf16(ap1, bv1, Oacc[dt], 0, 0, 0);
      }
    }
    __syncthreads();  // drains prefetch (vmcnt) + group done with buf
    buf ^= 1;
  }

  // in-block combine: group1 -> LDS (KV region now free) -> group0 adds
  float* F = (float*)KVb;
  int fbase = w4 * 1088;
  if (g == 1) {
    #pragma unroll
    for (int dt = 0; dt < 4; dt++)
      #pragma unroll
      for (int r = 0; r < 4; r++)
        F[fbase + (dt * 4 + r) * 64 + lane] = Oacc[dt][r];
    F[fbase + 1024 + lane] = lsum;
  }
  __syncthreads();
  if (g == 0) {
    #pragma unroll
    for (int dt = 0; dt < 4; dt++)
      #pragma unroll
      for (int r = 0; r < 4; r++)
        Oacc[dt][r] += F[fbase + (dt * 4 + r) * 64 + lane];
    lsum += F[fbase + 1024 + lane];
    // denominator: sum over quads (each lane's lsum is i=l partial)
    lsum += __shfl_xor(lsum, 16);
    lsum += __shfl_xor(lsum, 32);
    #pragma unroll
    for (int r = 0; r < 4; r++) {
      float lv = __shfl(lsum, quad * 4 + r);
      float inv = 1.0f / lv;
      int row = iblk + quad * 4 + r;
      size_t gi = qk_base + (size_t)row * 1024;
      #pragma unroll
      for (int dt = 0; dt < 4; dt++) {
        int d = dt * 16 + l;
        x1[gi + d] = x[gi + d] + Oacc[dt][r] * inv;
      }
    }
  }
}

extern "C" void kernel_launch(void* const* d_in, const int* in_sizes, int n_in,
                              void* d_out, int out_size, void* d_ws, size_t ws_size,
                              hipStream_t stream) {
  const float* x    = (const float*)d_in[0];
  const float* ln1g = (const float*)d_in[1];
  const float* ln1b = (const float*)d_in[2];
  const float* Wq   = (const float*)d_in[3];
  const float* bq   = (const float*)d_in[4];
  const float* Wk   = (const float*)d_in[5];
  const float* bk   = (const float*)d_in[6];
  const float* Wv   = (const float*)d_in[7];
  const float* bv   = (const float*)d_in[8];
  const float* ln2g = (const float*)d_in[9];
  const float* ln2b = (const float*)d_in[10];
  const float* W1   = (const float*)d_in[11];
  const float* b1   = (const float*)d_in[12];
  const float* W2   = (const float*)d_in[13];
  const float* b2   = (const float*)d_in[14];

  char* ws = (char*)d_ws;
  float* x1  = (float*)(ws + 0);            // 16 MB f32 [4096][1024]
  bf16* h    = (bf16*)(ws + 16777216);      //  8 MB bf16 [4096][1024]  (reused: FFN2 partial 3)
  bf16* WqkT = (bf16*)(ws + 25165824);      //  6 MB bf16 [3072][1024] (q|k|v)
  bf16* W1T  = (bf16*)(ws + 31457280);      //  8 MB [4096][1024]
  bf16* W2T  = (bf16*)(ws + 39845888);      //  8 MB [1024][4096]
  bf16* qb   = (bf16*)(ws + 48234496);      //  8 MB [4096][1024]  (reused: FFN2 partial 0)
  bf16* kb   = (bf16*)(ws + 56623104);      //  8 MB [4096][1024]  (reused: FFN2 partial 1)
  bf16* vt   = (bf16*)(ws + 65011712);      //  8 MB [b,h,d,t] = [2048][2048] (reused: FFN2 partial 2)
  bf16* act  = (bf16*)(ws + 73400320);      // 32 MB [4096][4096]

  static bool s_attr_done = false;
  if (!s_attr_done) {
    hipFuncSetAttribute(reinterpret_cast<const void*>(gemm_qkv),
                        hipFuncAttributeMaxDynamicSharedMemorySize, 131072);
    hipFuncSetAttribute(reinterpret_cast<const void*>(gemm_ffn1),
                        hipFuncAttributeMaxDynamicSharedMemorySize, 131072);
    hipFuncSetAttribute(reinterpret_cast<const void*>(gemm_ffn2),
                        hipFuncAttributeMaxDynamicSharedMemorySize, 131072);
    hipFuncSetAttribute(reinterpret_cast<const void*>(attn_mfma),
                        hipFuncAttributeMaxDynamicSharedMemorySize, 81920);
    s_attr_done = true;
  }

  prep_fused<<<15360, 256, 0, stream>>>(x, ln1g, ln1b, h,
                                        Wq, Wk, Wv, W1, W2, WqkT, W1T, W2T);
  gemm_qkv<<<192, 512, 131072, stream>>>(h, WqkT, bq, bk, bv, qb, kb, vt, 1024);
  attn_mfma<<<1024, 512, 81920, stream>>>(qb, kb, vt, x, x1);
  ln_kernel<<<4096, 256, 0, stream>>>(x1, ln2g, ln2b, h);
  gemm_ffn1<<<256, 512, 131072, stream>>>(h, W1T, b1, act, 4096, 1024);
  gemm_ffn2<<<256, 512, 131072, stream>>>(act, W2T,
      (unsigned short*)qb, (unsigned short*)kb, (unsigned short*)vt, (unsigned short*)h);
  reduce_ffn2<<<4096, 256, 0, stream>>>((const unsigned short*)qb, (const unsigned short*)kb,
                                        (const unsigned short*)vt, (const unsigned short*)h,
                                        x1, b2, (float*)d_out);
}

// Round 10
// 276.419 us; speedup vs baseline: 2.5148x; 1.0446x over previous
//
#include <hip/hip_runtime.h>
#include <hip/hip_bf16.h>
#include <math.h>

typedef __hip_bfloat16 bf16;
typedef __attribute__((ext_vector_type(8))) short bf16x8;
typedef __attribute__((ext_vector_type(4))) float f32x4;

__device__ __forceinline__ unsigned short f2bf_rne(float f) {
  unsigned u = __float_as_uint(f);
  u += 0x7fffu + ((u >> 16) & 1u);
  return (unsigned short)(u >> 16);
}
__device__ __forceinline__ float bf2f(unsigned short s) {
  return __uint_as_float(((unsigned)s) << 16);
}

// fast tanh-form GELU: max |diff| vs exact erf-GELU ~1e-3
__device__ __forceinline__ float gelu_fast(float v) {
  float u = v * (0.7978845608f + 0.0356774081f * v * v);
  float t = __builtin_amdgcn_exp2f(u * 2.8853900818f);
  float r = __builtin_amdgcn_rcpf(t + 1.0f);
  return v - v * r;
}

#define GLOBAL_AS __attribute__((address_space(1)))
#define LDS_AS __attribute__((address_space(3)))
__device__ __forceinline__ void gl2lds16(const void* g, void* l) {
  __builtin_amdgcn_global_load_lds((const GLOBAL_AS void*)g, (LDS_AS void*)l, 16, 0, 0);
}

// T1: XCD-chunked bijective swizzle (nwg % 8 == 0).
__device__ __forceinline__ int swz8(int f, int nwg) {
  return (f & 7) * (nwg >> 3) + (f >> 3);
}

// softmax scale folded into K at QKV time: 0.125 * log2(e)
#define SCALE_CS 0.18033688011112042f

// ---------------- LayerNorm body: x f32 [row][1024] -> h bf16 ----------------
__device__ __forceinline__ void ln_body(const float* __restrict__ x,
                                        const float* __restrict__ g,
                                        const float* __restrict__ b,
                                        bf16* __restrict__ h, int row, int t) {
  const float4 xv = ((const float4*)(x + (size_t)row * 1024))[t];
  float s = xv.x + xv.y + xv.z + xv.w;
  float sq = xv.x * xv.x + xv.y * xv.y + xv.z * xv.z + xv.w * xv.w;
  #pragma unroll
  for (int m = 1; m < 64; m <<= 1) { s += __shfl_xor(s, m); sq += __shfl_xor(sq, m); }
  __shared__ float ps[4], pq[4];
  if ((t & 63) == 0) { ps[t >> 6] = s; pq[t >> 6] = sq; }
  __syncthreads();
  s = ps[0] + ps[1] + ps[2] + ps[3];
  sq = pq[0] + pq[1] + pq[2] + pq[3];
  float mean = s * (1.0f / 1024.0f);
  float var = sq * (1.0f / 1024.0f) - mean * mean;
  float rs = rsqrtf(var + 1e-3f);
  float4 gv = ((const float4*)g)[t];
  float4 bv = ((const float4*)b)[t];
  ushort4 o;
  o.x = f2bf_rne((xv.x - mean) * rs * gv.x + bv.x);
  o.y = f2bf_rne((xv.y - mean) * rs * gv.y + bv.y);
  o.z = f2bf_rne((xv.z - mean) * rs * gv.z + bv.z);
  o.w = f2bf_rne((xv.w - mean) * rs * gv.w + bv.w);
  ((ushort4*)(h + (size_t)row * 1024))[t] = o;
}

__global__ __launch_bounds__(256) void ln_kernel(const float* __restrict__ x,
                                                 const float* __restrict__ g,
                                                 const float* __restrict__ b,
                                                 bf16* __restrict__ h) {
  ln_body(x, g, b, h, blockIdx.x, threadIdx.x);
}

// ------------- merged transpose + f32->bf16 for all 5 weights -------------
__device__ __forceinline__ void tr_tile(const float* __restrict__ W, bf16* __restrict__ WT,
                                        int R, int Cc, int bx, int by, int t) {
  __shared__ float tile[32][33];
  int tx = t & 31, ty = t >> 5;
  #pragma unroll
  for (int k = 0; k < 4; k++) {
    int rr = ty + k * 8;
    tile[rr][tx] = W[(size_t)(by + rr) * Cc + bx + tx];
  }
  __syncthreads();
  unsigned short* out = reinterpret_cast<unsigned short*>(WT);
  #pragma unroll
  for (int k = 0; k < 4; k++) {
    int rr = ty + k * 8;
    out[(size_t)(bx + rr) * R + by + tx] = f2bf_rne(tile[tx][rr]);
  }
}

// -------- fused prep: ln1 (blocks 0..4095) + weight transposes (rest) -------
__global__ __launch_bounds__(256) void prep_fused(const float* __restrict__ x,
                                                  const float* __restrict__ ln1g,
                                                  const float* __restrict__ ln1b,
                                                  bf16* __restrict__ h,
                                                  const float* __restrict__ Wq,
                                                  const float* __restrict__ Wk,
                                                  const float* __restrict__ Wv,
                                                  const float* __restrict__ W1,
                                                  const float* __restrict__ W2,
                                                  bf16* __restrict__ WqkT,
                                                  bf16* __restrict__ W1T,
                                                  bf16* __restrict__ W2T) {
  int id = blockIdx.x, t = threadIdx.x;
  if (id < 4096) { ln_body(x, ln1g, ln1b, h, id, t); return; }
  id -= 4096;
  if (id < 3072) {
    int sect = id >> 10, r = id & 1023;
    const float* W = sect == 0 ? Wq : (sect == 1 ? Wk : Wv);
    bf16* WT = WqkT + (size_t)sect * 1048576;
    tr_tile(W, WT, 1024, 1024, (r & 31) * 32, (r >> 5) * 32, t);
  } else if (id < 7168) {
    int r = id - 3072;
    tr_tile(W1, W1T, 1024, 4096, (r & 127) * 32, (r >> 7) * 32, t);
  } else {
    int r = id - 7168;
    tr_tile(W2, W2T, 4096, 1024, (r & 31) * 32, (r >> 5) * 32, t);
  }
}

// ============ 256x256 8-phase GEMM mainloop (T2+T3+T4+T5) ============
// (unchanged; see round-1 comment block for schedule derivation)
__device__ __forceinline__ void mainloop_256(const bf16* __restrict__ A,
                                             const bf16* __restrict__ BT,
                                             int lda, int nk, int m0, int n0,
                                             char* ldsb, int t,
                                             f32x4 (&acc)[8][4]) {
  const int lane = t & 63, wave = t >> 6;
  const int l = lane & 15, quad = lane >> 4;
  const int wm = (wave >> 2) * 128, wn = (wave & 3) * 64;
  const int srow = wave * 8 + (lane >> 3);          // row within 64-row round
  const int scol = ((lane & 7) ^ (lane >> 3)) * 8;  // pre-swizzled global col
  const int grp0 = (quad ^ (l & 7)) * 16;           // swizzled 16B group, k-slice 0
  const int grp1 = ((4 + quad) ^ (l & 7)) * 16;     // k-slice 1

  bf16x8 a[4][2], b01[2][2], b23[2][2];

  auto stA = [&](int buf, int half, int kt) {
    const bf16* s = A + (size_t)(m0 + half * 128 + srow) * lda + kt * 64 + scol;
    char* d = ldsb + buf * 65536 + half * 16384 + wave * 1024;
    gl2lds16(s, d);
    gl2lds16(s + (size_t)64 * lda, d + 8192);
  };
  auto stB = [&](int buf, int half, int kt) {
    const bf16* s = BT + (size_t)(n0 + half * 128 + srow) * lda + kt * 64 + scol;
    char* d = ldsb + buf * 65536 + 32768 + half * 16384 + wave * 1024;
    gl2lds16(s, d);
    gl2lds16(s + (size_t)64 * lda, d + 8192);
  };
  auto rdA = [&](int buf, int mh) {
    const char* base = ldsb + buf * 65536 + (wm + mh * 64 + l) * 128;
    #pragma unroll
    for (int ii = 0; ii < 4; ii++) {
      a[ii][0] = *(const bf16x8*)(base + ii * 2048 + grp0);
      a[ii][1] = *(const bf16x8*)(base + ii * 2048 + grp1);
    }
  };
  auto rdB = [&](int buf, int nh, bf16x8 (&bb)[2][2]) {
    const char* base = ldsb + buf * 65536 + 32768 + (wn + nh * 32 + l) * 128;
    #pragma unroll
    for (int jj = 0; jj < 2; jj++) {
      bb[jj][0] = *(const bf16x8*)(base + jj * 2048 + grp0);
      bb[jj][1] = *(const bf16x8*)(base + jj * 2048 + grp1);
    }
  };
  auto mm4 = [&](int mi, bf16x8 (&bb)[2][2], int nj) {
    #pragma unroll
    for (int ii = 0; ii < 4; ii++)
      #pragma unroll
      for (int jj = 0; jj < 2; jj++) {
        acc[mi + ii][nj + jj] = __builtin_amdgcn_mfma_f32_16x16x32_bf16(
            a[ii][0], bb[jj][0], acc[mi + ii][nj + jj], 0, 0, 0);
        acc[mi + ii][nj + jj] = __builtin_amdgcn_mfma_f32_16x16x32_bf16(
            a[ii][1], bb[jj][1], acc[mi + ii][nj + jj], 0, 0, 0);
      }
  };

#define BARX() __builtin_amdgcn_s_barrier()
#define LGKM0() do { asm volatile("s_waitcnt lgkmcnt(0)" ::: "memory"); \
                     __builtin_amdgcn_sched_barrier(0); } while (0)
#define HALF4(BC, DOA, SAB, SAK, DOB, SBB, SBK, VMN)                      \
  do {                                                                    \
    rdA(BC, 0); rdB(BC, 0, b01);                                          \
    if (DOA) stA(SAB, 0, SAK);                                            \
    BARX(); LGKM0();                                                      \
    __builtin_amdgcn_s_setprio(1); mm4(0, b01, 0);                        \
    __builtin_amdgcn_s_setprio(0); BARX();                                \
    rdB(BC, 1, b23);                                                      \
    if (DOA) stA(SAB, 1, SAK);                                            \
    BARX(); LGKM0();                                                      \
    __builtin_amdgcn_s_setprio(1); mm4(0, b23, 2);                        \
    __builtin_amdgcn_s_setprio(0); BARX();                                \
    rdA(BC, 1);                                                           \
    if (DOB) stB(SBB, 0, SBK);                                            \
    BARX(); LGKM0();                                                      \
    __builtin_amdgcn_s_setprio(1); mm4(4, b01, 0);                        \
    __builtin_amdgcn_s_setprio(0); BARX();                                \
    if (DOB) stB(SBB, 1, SBK);                                            \
    BARX();                                                               \
    __builtin_amdgcn_s_setprio(1); mm4(4, b23, 2);                        \
    __builtin_amdgcn_s_setprio(0);                                        \
    asm volatile("s_waitcnt vmcnt(" VMN ")" ::: "memory");                \
    BARX();                                                               \
  } while (0)

  const int nt = nk >> 6;
  // prologue: tile0 (8 loads) + tile1.B (4 loads); vmcnt(4) -> tile0 landed
  stA(0, 0, 0); stA(0, 1, 0);
  stB(0, 0, 0); stB(0, 1, 0);
  stB(1, 0, 1); stB(1, 1, 1);
  asm volatile("s_waitcnt vmcnt(4)" ::: "memory");
  BARX();
  int tt = 0;
  for (; tt + 2 < nt; tt += 2) {
    HALF4(0, 1, 1, tt + 1, 1, 0, tt + 2, "4");
    HALF4(1, 1, 0, tt + 2, 1, 1, tt + 3, "4");
  }
  // tail: tt = nt-2; stage only (nt-1).A, drain fully before last tile
  HALF4(0, 1, 1, tt + 1, 0, 0, 0, "0");
  HALF4(1, 0, 0, 0, 0, 0, 0, "0");
#undef HALF4
#undef LGKM0
#undef BARX
}

// ---------------- FFN1: act bf16 = gelu(h @ W1 + b1), N=4096 K=1024 ---------
__global__ __launch_bounds__(512, 2) void gemm_ffn1(const bf16* __restrict__ A,
                                                    const bf16* __restrict__ BT,
                                                    const float* __restrict__ bias,
                                                    bf16* __restrict__ out,
                                                    int N, int K) {
  extern __shared__ char lds[];
  int t = threadIdx.x;
  int nf = swz8(blockIdx.x, gridDim.x);
  int n0 = (nf & 15) * 256, m0 = (nf >> 4) * 256;
  f32x4 acc[8][4];
  #pragma unroll
  for (int i = 0; i < 8; i++)
    #pragma unroll
    for (int j = 0; j < 4; j++) acc[i][j] = (f32x4){0.f, 0.f, 0.f, 0.f};
  mainloop_256(A, BT, K, K, m0, n0, lds, t, acc);

  int lane = t & 63, wave = t >> 6;
  int l = lane & 15, quad = lane >> 4;
  int wm = (wave >> 2) * 128, wn = (wave & 3) * 64;
  int r4 = quad * 4;
  unsigned short* os = reinterpret_cast<unsigned short*>(out);
  #pragma unroll
  for (int i = 0; i < 8; i++)
    #pragma unroll
    for (int j = 0; j < 4; j++) {
      int col = n0 + wn + j * 16 + l;
      float bval = bias[col];
      #pragma unroll
      for (int r = 0; r < 4; r++) {
        int row = m0 + wm + i * 16 + r4 + r;
        os[(size_t)row * N + col] = f2bf_rne(gelu_fast(acc[i][j][r] + bval));
      }
    }
}

// ------- FFN2 split-K (8-phase): partial[z] bf16 = act[:,z] @ W2T[:,z] ------
__global__ __launch_bounds__(512, 2) void gemm_ffn2(const bf16* __restrict__ A,
                                                    const bf16* __restrict__ BT,
                                                    unsigned short* __restrict__ p0,
                                                    unsigned short* __restrict__ p1,
                                                    unsigned short* __restrict__ p2,
                                                    unsigned short* __restrict__ p3) {
  extern __shared__ char lds[];
  int t = threadIdx.x;
  int nf = swz8(blockIdx.x, gridDim.x);
  int n0 = (nf & 3) * 256, m0 = ((nf >> 2) & 15) * 256;
  int z = nf >> 6;
  f32x4 acc[8][4];
  #pragma unroll
  for (int i = 0; i < 8; i++)
    #pragma unroll
    for (int j = 0; j < 4; j++) acc[i][j] = (f32x4){0.f, 0.f, 0.f, 0.f};
  mainloop_256(A + z * 1024, BT + z * 1024, 4096, 1024, m0, n0, lds, t, acc);

  unsigned short* p = z == 0 ? p0 : (z == 1 ? p1 : (z == 2 ? p2 : p3));
  int lane = t & 63, wave = t >> 6;
  int l = lane & 15, quad = lane >> 4;
  int wm = (wave >> 2) * 128, wn = (wave & 3) * 64;
  int r4 = quad * 4;
  #pragma unroll
  for (int i = 0; i < 8; i++)
    #pragma unroll
    for (int j = 0; j < 4; j++) {
      int col = n0 + wn + j * 16 + l;
      #pragma unroll
      for (int r = 0; r < 4; r++) {
        int row = m0 + wm + i * 16 + r4 + r;
        p[(size_t)row * 1024 + col] = f2bf_rne(acc[i][j][r]);
      }
    }
}

// -------- FFN2 reduce: out f32 = p0 + p1 + p2 + p3 + bias + x1 --------
__global__ __launch_bounds__(256) void reduce_ffn2(const unsigned short* __restrict__ p0,
                                                   const unsigned short* __restrict__ p1,
                                                   const unsigned short* __restrict__ p2,
                                                   const unsigned short* __restrict__ p3,
                                                   const float* __restrict__ x1,
                                                   const float* __restrict__ bias,
                                                   float* __restrict__ out) {
  int row = blockIdx.x, t = threadIdx.x;
  size_t base = (size_t)row * 1024;
  ushort4 a = ((const ushort4*)(p0 + base))[t];
  ushort4 b = ((const ushort4*)(p1 + base))[t];
  ushort4 c = ((const ushort4*)(p2 + base))[t];
  ushort4 d = ((const ushort4*)(p3 + base))[t];
  float4 xv = ((const float4*)(x1 + base))[t];
  float4 bv = ((const float4*)bias)[t];
  float4 o;
  o.x = (bf2f(a.x) + bf2f(b.x)) + (bf2f(c.x) + bf2f(d.x)) + xv.x + bv.x;
  o.y = (bf2f(a.y) + bf2f(b.y)) + (bf2f(c.y) + bf2f(d.y)) + xv.y + bv.y;
  o.z = (bf2f(a.z) + bf2f(b.z)) + (bf2f(c.z) + bf2f(d.z)) + xv.z + bv.z;
  o.w = (bf2f(a.w) + bf2f(b.w)) + (bf2f(c.w) + bf2f(d.w)) + xv.w + bv.w;
  ((float4*)(out + base))[t] = o;
}

// ------------- fused QKV GEMM: N=3072 (q|k|v) -------------
// k written pre-scaled by SCALE_CS (softmax scale folded in);
// v written transposed via LDS staging -> coalesced 512B row writes
// (old path: 8B stores at 4KB stride = ~4x write amplification).
__global__ __launch_bounds__(512, 2) void gemm_qkv(const bf16* __restrict__ A,
                                                   const bf16* __restrict__ BT,
                                                   const float* __restrict__ bq,
                                                   const float* __restrict__ bk,
                                                   const float* __restrict__ bv,
                                                   bf16* __restrict__ qb,
                                                   bf16* __restrict__ kb,
                                                   bf16* __restrict__ vt,
                                                   int K) {
  extern __shared__ char lds[];
  int t = threadIdx.x;
  int nf = swz8(blockIdx.x, gridDim.x);
  int n0 = (nf % 12) * 256, m0 = (nf / 12) * 256;
  f32x4 acc[8][4];
  #pragma unroll
  for (int i = 0; i < 8; i++)
    #pragma unroll
    for (int j = 0; j < 4; j++) acc[i][j] = (f32x4){0.f, 0.f, 0.f, 0.f};
  mainloop_256(A, BT, K, K, m0, n0, lds, t, acc);

  int lane = t & 63, wave = t >> 6;
  int l = lane & 15, quad = lane >> 4;
  int wm = (wave >> 2) * 128, wn = (wave & 3) * 64;
  int sect = n0 >> 10;  // 0=q 1=k 2=v (BN=256 divides 1024 sections)
  const float* bias = sect == 0 ? bq : (sect == 1 ? bk : bv);
  int r4 = quad * 4;
  if (sect < 2) {
    bf16* o = sect == 0 ? qb : kb;
    unsigned short* os = reinterpret_cast<unsigned short*>(o);
    float scl = sect == 1 ? SCALE_CS : 1.0f;
    #pragma unroll
    for (int i = 0; i < 8; i++)
      #pragma unroll
      for (int j = 0; j < 4; j++) {
        int col = n0 + wn + j * 16 + l;
        int c1 = col & 1023;
        float bval = bias[c1];
        int row0 = m0 + wm + i * 16 + r4;
        #pragma unroll
        for (int r = 0; r < 4; r++)
          os[(size_t)(row0 + r) * 1024 + c1] = f2bf_rne((acc[i][j][r] + bval) * scl);
      }
  } else {
    // stage (c, t) transposed tile in LDS (8B-group XOR swizzle), then
    // each wave writes full 512B vt rows, coalesced.
    unsigned short* Ls = (unsigned short*)lds;
    #pragma unroll
    for (int i = 0; i < 8; i++)
      #pragma unroll
      for (int j = 0; j < 4; j++) {
        int c1l = wn + j * 16 + l;                  // 0..255 (local d-col)
        float bval = bias[(n0 - 2048) + c1l];
        ushort4 pk;
        pk.x = f2bf_rne(acc[i][j][0] + bval);
        pk.y = f2bf_rne(acc[i][j][1] + bval);
        pk.z = f2bf_rne(acc[i][j][2] + bval);
        pk.w = f2bf_rne(acc[i][j][3] + bval);
        int gq = ((wm + i * 16) >> 2) + quad;       // 8B group (4 rows) 0..63
        *(ushort4*)((char*)Ls + c1l * 512 + ((gq ^ (c1l & 15)) << 3)) = pk;
      }
    __syncthreads();
    int bb = m0 >> 11, t0b = m0 & 2047;
    size_t vbase = ((size_t)(bb * 1024 + (n0 - 2048))) * 2048 + t0b;
    #pragma unroll 4
    for (int it2 = 0; it2 < 32; it2++) {
      int c1row = it2 * 8 + wave;
      uint2 v = *(const uint2*)((char*)Ls + c1row * 512 +
                                ((lane ^ (c1row & 15)) << 3));
      *(uint2*)((unsigned short*)vt + vbase + (size_t)c1row * 2048 + lane * 4) = v;
    }
  }
}

// ---------------- MFMA flash attention v9 ----------------
// v7 structure + XCD-chunked bh mapping. Softmax scale pre-folded into K
// (no per-score mul); row-sums (softmax denominator) computed via
// ones-MFMA on the packed bf16 P (matrix pipe, C-layout delivers lv
// directly per lane -> no scalar adds, no shuffles).
__global__ __launch_bounds__(512, 4) void attn_mfma(const bf16* __restrict__ qb,
                                                    const bf16* __restrict__ kb,
                                                    const bf16* __restrict__ vt,
                                                    const float* __restrict__ x,
                                                    float* __restrict__ x1) {
  extern __shared__ char alds[];
  char* KVb = alds;           // 64KB: g*32768 + buf*16384 + (K:0|V:8192) + w4*2048
  char* Pb  = alds + 65536;   // 16KB: wave*2048, row l stride 128B
  int t = threadIdx.x;
  int nf = swz8(blockIdx.x, 1024);
  int chunk = nf >> 7, local = nf & 127;
  int y = local >> 2;                 // 0..31, ascending = largest-first
  int bh = chunk * 4 + (local & 3);   // 4 heads per XCD chunk
  int b = bh >> 4, h = bh & 15;
  size_t qk_base = (size_t)b * 2048 * 1024 + (size_t)h * 64;
  size_t vt_base = (size_t)bh * 64 * 2048;
  int lane = t & 63, wave = t >> 6;
  int g = wave >> 2, w4 = wave & 3;
  int l = lane & 15, quad = lane >> 4;
  int sw = l & 7;
  int srow8 = lane >> 3;                       // staging row-in-8 (0..7)
  int scol = ((lane & 7) ^ srow8) * 8;         // swizzled source col (elems)
  int it = 31 - y;                             // largest first
  int i0 = it * 64;
  int njt = it + 1;
  int iblk = i0 + w4 * 16;

  bf16x8 ones;
  #pragma unroll
  for (int z = 0; z < 8; z++) ones[z] = (short)0x3F80;  // bf16 1.0

  // prologue: waves 0-3 stage Q (into P region) + group0 KV tile0;
  // waves 4-7 stage group1 KV tile1 (if it exists)
  if (g == 0) {
    #pragma unroll
    for (int c = 0; c < 2; c++) {
      int rr = w4 * 16 + c * 8 + srow8;
      gl2lds16(kb + qk_base + (size_t)(i0 + rr) * 1024 + scol,
               Pb + w4 * 2048 + c * 1024);
      gl2lds16(qb + qk_base + (size_t)rr * 1024 + scol,
               KVb + w4 * 2048 + c * 1024);
      gl2lds16(vt + vt_base + (size_t)rr * 2048 + scol,
               KVb + 8192 + w4 * 2048 + c * 1024);
    }
  } else if (njt > 1) {
    #pragma unroll
    for (int c = 0; c < 2; c++) {
      int rr = w4 * 16 + c * 8 + srow8;
      gl2lds16(qb + qk_base + (size_t)(64 + rr) * 1024 + scol,
               KVb + 32768 + w4 * 2048 + c * 1024);
      gl2lds16(vt + vt_base + (size_t)rr * 2048 + 64 + scol,
               KVb + 32768 + 8192 + w4 * 2048 + c * 1024);
    }
  }
  __syncthreads();  // drains vmcnt: Q + first tiles visible

  const char* qr = Pb + w4 * 2048 + l * 128;
  bf16x8 qf0 = *(const bf16x8*)(qr + ((quad ^ sw) * 16));
  bf16x8 qf1 = *(const bf16x8*)(qr + (((4 + quad) ^ sw) * 16));
  __syncthreads();  // all waves hold Q in regs; P region may be overlaid now

  f32x4 Oacc[4], Ol;
  #pragma unroll
  for (int dt = 0; dt < 4; dt++) Oacc[dt] = (f32x4){0.f, 0.f, 0.f, 0.f};
  Ol = (f32x4){0.f, 0.f, 0.f, 0.f};

  char* Pw = Pb + wave * 2048 + l * 128;  // own-wave P row base
  char* KVg = KVb + g * 32768;
  int nstep = (njt + 1) >> 1;
  int buf = 0;
  for (int s = 0; s < nstep; s++) {
    int jt = 2 * s + g;
    // prefetch my group's tile jt+2 into other buffer
    if (jt + 2 < njt) {
      int j1 = (jt + 2) * 64;
      #pragma unroll
      for (int c = 0; c < 2; c++) {
        int rr = w4 * 16 + c * 8 + srow8;
        gl2lds16(qb + qk_base + (size_t)(j1 + rr) * 1024 + scol,
                 KVg + (buf ^ 1) * 16384 + w4 * 2048 + c * 1024);
        gl2lds16(vt + vt_base + (size_t)rr * 2048 + j1 + scol,
                 KVg + (buf ^ 1) * 16384 + 8192 + w4 * 2048 + c * 1024);
      }
    }
    if (jt < njt) {
      int j0v = jt * 64;
      // S^T per nt: A = rows from qb (m=j), B = pre-scaled frag from kb (n=i)
      const bf16* Kb = (const bf16*)(KVg + buf * 16384);
      #pragma unroll
      for (int nt = 0; nt < 4; nt++) {
        int jb = j0v + nt * 16;
        uint2 pk;
        if (jb > iblk + 15) {  // fully masked
          pk.x = 0u; pk.y = 0u;
        } else {
          const bf16* kr = Kb + (nt * 16 + l) * 64;
          bf16x8 kf0 = *(const bf16x8*)(kr + ((quad ^ sw) * 8));
          bf16x8 kf1 = *(const bf16x8*)(kr + (((4 + quad) ^ sw) * 8));
          f32x4 sv = (f32x4){0.f, 0.f, 0.f, 0.f};
          sv = __builtin_amdgcn_mfma_f32_16x16x32_bf16(kf0, qf0, sv, 0, 0, 0);
          sv = __builtin_amdgcn_mfma_f32_16x16x32_bf16(kf1, qf1, sv, 0, 0, 0);
          float p0, p1, p2, p3;
          if (jb + 15 <= iblk) {  // fully unmasked
            p0 = __builtin_amdgcn_exp2f(sv[0]);
            p1 = __builtin_amdgcn_exp2f(sv[1]);
            p2 = __builtin_amdgcn_exp2f(sv[2]);
            p3 = __builtin_amdgcn_exp2f(sv[3]);
          } else {                // diagonal straddle
            int i_ = iblk + l, jbase = jb + quad * 4;
            p0 = (jbase + 0 > i_) ? 0.f : __builtin_amdgcn_exp2f(sv[0]);
            p1 = (jbase + 1 > i_) ? 0.f : __builtin_amdgcn_exp2f(sv[1]);
            p2 = (jbase + 2 > i_) ? 0.f : __builtin_amdgcn_exp2f(sv[2]);
            p3 = (jbase + 3 > i_) ? 0.f : __builtin_amdgcn_exp2f(sv[3]);
          }
          union { __hip_bfloat162 h2; unsigned u; } c0u, c1u;
          c0u.h2 = __float22bfloat162_rn(make_float2(p0, p1));
          c1u.h2 = __float22bfloat162_rn(make_float2(p2, p3));
          pk.x = c0u.u; pk.y = c1u.u;
        }
        // P row byte offset: 16B group g16=nt*2+(quad>>1) swizzled by sw
        *(uint2*)(Pw + (((nt * 2 + (quad >> 1)) ^ sw) << 4) + ((quad & 1) << 3)) = pk;
      }
      asm volatile("s_waitcnt lgkmcnt(0)" ::: "memory");  // own-wave P only

      // PV: A = P rows (m=i), B = V rows (n=d); +ones-MFMA for row sums
      bf16x8 ap0 = *(const bf16x8*)(Pw + ((quad ^ sw) << 4));
      bf16x8 ap1 = *(const bf16x8*)(Pw + (((4 + quad) ^ sw) << 4));
      const bf16* Vb = (const bf16*)(KVg + buf * 16384 + 8192);
      #pragma unroll
      for (int dt = 0; dt < 4; dt++) {
        const bf16* vr = Vb + (dt * 16 + l) * 64;
        bf16x8 bv0 = *(const bf16x8*)(vr + ((quad ^ sw) * 8));
        bf16x8 bv1 = *(const bf16x8*)(vr + (((4 + quad) ^ sw) * 8));
        Oacc[dt] = __builtin_amdgcn_mfma_f32_16x16x32_bf16(ap0, bv0, Oacc[dt], 0, 0, 0);
        Oacc[dt] = __builtin_amdgcn_mfma_f32_16x16x32_bf16(ap1, bv1, Oacc[dt], 0, 0, 0);
      }
      Ol = __builtin_amdgcn_mfma_f32_16x16x32_bf16(ap0, ones, Ol, 0, 0, 0);
      Ol = __builtin_amdgcn_mfma_f32_16x16x32_bf16(ap1, ones, Ol, 0, 0, 0);
    }
    __syncthreads();  // drains prefetch (vmcnt) + group done with buf
    buf ^= 1;
  }

  // in-block combine: group1 -> LDS (KV region now free) -> group0 adds
  float* F = (float*)KVb;
  int fbase = w4 * 1280;
  if (g == 1) {
    #pragma unroll
    for (int dt = 0; dt < 4; dt++)
      #pragma unroll
      for (int r = 0; r < 4; r++)
        F[fbase + (dt * 4 + r) * 64 + lane] = Oacc[dt][r];
    #pragma unroll
    for (int r = 0; r < 4; r++)
      F[fbase + 1024 + r * 64 + lane] = Ol[r];
  }
  __syncthreads();
  if (g == 0) {
    #pragma unroll
    for (int dt = 0; dt < 4; dt++)
      #pragma unroll
      for (int r = 0; r < 4; r++)
        Oacc[dt][r] += F[fbase + (dt * 4 + r) * 64 + lane];
    #pragma unroll
    for (int r = 0; r < 4; r++)
      Ol[r] += F[fbase + 1024 + r * 64 + lane];
    // lane (quad,l): Ol[r] = rowsum for row quad*4+r (same in every col l)
    #pragma unroll
    for (int r = 0; r < 4; r++) {
      float inv = 1.0f / Ol[r];
      int row = iblk + quad * 4 + r;
      size_t gi = qk_base + (size_t)row * 1024;
      #pragma unroll
      for (int dt = 0; dt < 4; dt++) {
        int d = dt * 16 + l;
        x1[gi + d] = x[gi + d] + Oacc[dt][r] * inv;
      }
    }
  }
}

extern "C" void kernel_launch(void* const* d_in, const int* in_sizes, int n_in,
                              void* d_out, int out_size, void* d_ws, size_t ws_size,
                              hipStream_t stream) {
  const float* x    = (const float*)d_in[0];
  const float* ln1g = (const float*)d_in[1];
  const float* ln1b = (const float*)d_in[2];
  const float* Wq   = (const float*)d_in[3];
  const float* bq   = (const float*)d_in[4];
  const float* Wk   = (const float*)d_in[5];
  const float* bk   = (const float*)d_in[6];
  const float* Wv   = (const float*)d_in[7];
  const float* bv   = (const float*)d_in[8];
  const float* ln2g = (const float*)d_in[9];
  const float* ln2b = (const float*)d_in[10];
  const float* W1   = (const float*)d_in[11];
  const float* b1   = (const float*)d_in[12];
  const float* W2   = (const float*)d_in[13];
  const float* b2   = (const float*)d_in[14];

  char* ws = (char*)d_ws;
  float* x1  = (float*)(ws + 0);            // 16 MB f32 [4096][1024]
  bf16* h    = (bf16*)(ws + 16777216);      //  8 MB bf16 [4096][1024]  (reused: FFN2 partial 3)
  bf16* WqkT = (bf16*)(ws + 25165824);      //  6 MB bf16 [3072][1024] (q|k|v)
  bf16* W1T  = (bf16*)(ws + 31457280);      //  8 MB [4096][1024]
  bf16* W2T  = (bf16*)(ws + 39845888);      //  8 MB [1024][4096]
  bf16* qb   = (bf16*)(ws + 48234496);      //  8 MB [4096][1024]  (reused: FFN2 partial 0)
  bf16* kb   = (bf16*)(ws + 56623104);      //  8 MB [4096][1024]  (reused: FFN2 partial 1)
  bf16* vt   = (bf16*)(ws + 65011712);      //  8 MB [b,h,d,t] = [2048][2048] (reused: FFN2 partial 2)
  bf16* act  = (bf16*)(ws + 73400320);      // 32 MB [4096][4096]

  static bool s_attr_done = false;
  if (!s_attr_done) {
    hipFuncSetAttribute(reinterpret_cast<const void*>(gemm_qkv),
                        hipFuncAttributeMaxDynamicSharedMemorySize, 131072);
    hipFuncSetAttribute(reinterpret_cast<const void*>(gemm_ffn1),
                        hipFuncAttributeMaxDynamicSharedMemorySize, 131072);
    hipFuncSetAttribute(reinterpret_cast<const void*>(gemm_ffn2),
                        hipFuncAttributeMaxDynamicSharedMemorySize, 131072);
    hipFuncSetAttribute(reinterpret_cast<const void*>(attn_mfma),
                        hipFuncAttributeMaxDynamicSharedMemorySize, 81920);
    s_attr_done = true;
  }

  prep_fused<<<15360, 256, 0, stream>>>(x, ln1g, ln1b, h,
                                        Wq, Wk, Wv, W1, W2, WqkT, W1T, W2T);
  gemm_qkv<<<192, 512, 131072, stream>>>(h, WqkT, bq, bk, bv, qb, kb, vt, 1024);
  attn_mfma<<<1024, 512, 81920, stream>>>(qb, kb, vt, x, x1);
  ln_kernel<<<4096, 256, 0, stream>>>(x1, ln2g, ln2b, h);
  gemm_ffn1<<<256, 512, 131072, stream>>>(h, W1T, b1, act, 4096, 1024);
  gemm_ffn2<<<256, 512, 131072, stream>>>(act, W2T,
      (unsigned short*)qb, (unsigned short*)kb, (unsigned short*)vt, (unsigned short*)h);
  reduce_ffn2<<<4096, 256, 0, stream>>>((const unsigned short*)qb, (const unsigned short*)kb,
                                        (const unsigned short*)vt, (const unsigned short*)h,
                                        x1, b2, (float*)d_out);
}

// Round 11
// 275.766 us; speedup vs baseline: 2.5208x; 1.0024x over previous
//
#include <hip/hip_runtime.h>
#include <hip/hip_bf16.h>
#include <math.h>

typedef __hip_bfloat16 bf16;
typedef __attribute__((ext_vector_type(8))) short bf16x8;
typedef __attribute__((ext_vector_type(4))) float f32x4;

__device__ __forceinline__ unsigned short f2bf_rne(float f) {
  unsigned u = __float_as_uint(f);
  u += 0x7fffu + ((u >> 16) & 1u);
  return (unsigned short)(u >> 16);
}
__device__ __forceinline__ float bf2f(unsigned short s) {
  return __uint_as_float(((unsigned)s) << 16);
}

// fast tanh-form GELU: max |diff| vs exact erf-GELU ~1e-3
__device__ __forceinline__ float gelu_fast(float v) {
  float u = v * (0.7978845608f + 0.0356774081f * v * v);
  float t = __builtin_amdgcn_exp2f(u * 2.8853900818f);
  float r = __builtin_amdgcn_rcpf(t + 1.0f);
  return v - v * r;
}

#define GLOBAL_AS __attribute__((address_space(1)))
#define LDS_AS __attribute__((address_space(3)))
__device__ __forceinline__ void gl2lds16(const void* g, void* l) {
  __builtin_amdgcn_global_load_lds((const GLOBAL_AS void*)g, (LDS_AS void*)l, 16, 0, 0);
}

// T1: XCD-chunked bijective swizzle (nwg % 8 == 0).
__device__ __forceinline__ int swz8(int f, int nwg) {
  return (f & 7) * (nwg >> 3) + (f >> 3);
}

// softmax scale folded into K at QKV time: 0.125 * log2(e)
#define SCALE_CS 0.18033688011112042f

// ---------------- LayerNorm body: x f32 [row][1024] -> h bf16 ----------------
__device__ __forceinline__ void ln_body(const float* __restrict__ x,
                                        const float* __restrict__ g,
                                        const float* __restrict__ b,
                                        bf16* __restrict__ h, int row, int t) {
  const float4 xv = ((const float4*)(x + (size_t)row * 1024))[t];
  float s = xv.x + xv.y + xv.z + xv.w;
  float sq = xv.x * xv.x + xv.y * xv.y + xv.z * xv.z + xv.w * xv.w;
  #pragma unroll
  for (int m = 1; m < 64; m <<= 1) { s += __shfl_xor(s, m); sq += __shfl_xor(sq, m); }
  __shared__ float ps[4], pq[4];
  if ((t & 63) == 0) { ps[t >> 6] = s; pq[t >> 6] = sq; }
  __syncthreads();
  s = ps[0] + ps[1] + ps[2] + ps[3];
  sq = pq[0] + pq[1] + pq[2] + pq[3];
  float mean = s * (1.0f / 1024.0f);
  float var = sq * (1.0f / 1024.0f) - mean * mean;
  float rs = rsqrtf(var + 1e-3f);
  float4 gv = ((const float4*)g)[t];
  float4 bv = ((const float4*)b)[t];
  ushort4 o;
  o.x = f2bf_rne((xv.x - mean) * rs * gv.x + bv.x);
  o.y = f2bf_rne((xv.y - mean) * rs * gv.y + bv.y);
  o.z = f2bf_rne((xv.z - mean) * rs * gv.z + bv.z);
  o.w = f2bf_rne((xv.w - mean) * rs * gv.w + bv.w);
  ((ushort4*)(h + (size_t)row * 1024))[t] = o;
}

__global__ __launch_bounds__(256) void ln_kernel(const float* __restrict__ x,
                                                 const float* __restrict__ g,
                                                 const float* __restrict__ b,
                                                 bf16* __restrict__ h) {
  ln_body(x, g, b, h, blockIdx.x, threadIdx.x);
}

// ------------- merged transpose + f32->bf16 for all 5 weights -------------
__device__ __forceinline__ void tr_tile(const float* __restrict__ W, bf16* __restrict__ WT,
                                        int R, int Cc, int bx, int by, int t) {
  __shared__ float tile[32][33];
  int tx = t & 31, ty = t >> 5;
  #pragma unroll
  for (int k = 0; k < 4; k++) {
    int rr = ty + k * 8;
    tile[rr][tx] = W[(size_t)(by + rr) * Cc + bx + tx];
  }
  __syncthreads();
  unsigned short* out = reinterpret_cast<unsigned short*>(WT);
  #pragma unroll
  for (int k = 0; k < 4; k++) {
    int rr = ty + k * 8;
    out[(size_t)(bx + rr) * R + by + tx] = f2bf_rne(tile[tx][rr]);
  }
}

// -------- fused prep: ln1 (blocks 0..4095) + weight transposes (rest) -------
__global__ __launch_bounds__(256) void prep_fused(const float* __restrict__ x,
                                                  const float* __restrict__ ln1g,
                                                  const float* __restrict__ ln1b,
                                                  bf16* __restrict__ h,
                                                  const float* __restrict__ Wq,
                                                  const float* __restrict__ Wk,
                                                  const float* __restrict__ Wv,
                                                  const float* __restrict__ W1,
                                                  const float* __restrict__ W2,
                                                  bf16* __restrict__ WqkT,
                                                  bf16* __restrict__ W1T,
                                                  bf16* __restrict__ W2T) {
  int id = blockIdx.x, t = threadIdx.x;
  if (id < 4096) { ln_body(x, ln1g, ln1b, h, id, t); return; }
  id -= 4096;
  if (id < 3072) {
    int sect = id >> 10, r = id & 1023;
    const float* W = sect == 0 ? Wq : (sect == 1 ? Wk : Wv);
    bf16* WT = WqkT + (size_t)sect * 1048576;
    tr_tile(W, WT, 1024, 1024, (r & 31) * 32, (r >> 5) * 32, t);
  } else if (id < 7168) {
    int r = id - 3072;
    tr_tile(W1, W1T, 1024, 4096, (r & 127) * 32, (r >> 7) * 32, t);
  } else {
    int r = id - 7168;
    tr_tile(W2, W2T, 4096, 1024, (r & 31) * 32, (r >> 5) * 32, t);
  }
}

// ============ 256x256 8-phase GEMM mainloop (T2+T3+T4+T5) ============
// (unchanged; see round-1 comment block for schedule derivation)
__device__ __forceinline__ void mainloop_256(const bf16* __restrict__ A,
                                             const bf16* __restrict__ BT,
                                             int lda, int nk, int m0, int n0,
                                             char* ldsb, int t,
                                             f32x4 (&acc)[8][4]) {
  const int lane = t & 63, wave = t >> 6;
  const int l = lane & 15, quad = lane >> 4;
  const int wm = (wave >> 2) * 128, wn = (wave & 3) * 64;
  const int srow = wave * 8 + (lane >> 3);          // row within 64-row round
  const int scol = ((lane & 7) ^ (lane >> 3)) * 8;  // pre-swizzled global col
  const int grp0 = (quad ^ (l & 7)) * 16;           // swizzled 16B group, k-slice 0
  const int grp1 = ((4 + quad) ^ (l & 7)) * 16;     // k-slice 1

  bf16x8 a[4][2], b01[2][2], b23[2][2];

  auto stA = [&](int buf, int half, int kt) {
    const bf16* s = A + (size_t)(m0 + half * 128 + srow) * lda + kt * 64 + scol;
    char* d = ldsb + buf * 65536 + half * 16384 + wave * 1024;
    gl2lds16(s, d);
    gl2lds16(s + (size_t)64 * lda, d + 8192);
  };
  auto stB = [&](int buf, int half, int kt) {
    const bf16* s = BT + (size_t)(n0 + half * 128 + srow) * lda + kt * 64 + scol;
    char* d = ldsb + buf * 65536 + 32768 + half * 16384 + wave * 1024;
    gl2lds16(s, d);
    gl2lds16(s + (size_t)64 * lda, d + 8192);
  };
  auto rdA = [&](int buf, int mh) {
    const char* base = ldsb + buf * 65536 + (wm + mh * 64 + l) * 128;
    #pragma unroll
    for (int ii = 0; ii < 4; ii++) {
      a[ii][0] = *(const bf16x8*)(base + ii * 2048 + grp0);
      a[ii][1] = *(const bf16x8*)(base + ii * 2048 + grp1);
    }
  };
  auto rdB = [&](int buf, int nh, bf16x8 (&bb)[2][2]) {
    const char* base = ldsb + buf * 65536 + 32768 + (wn + nh * 32 + l) * 128;
    #pragma unroll
    for (int jj = 0; jj < 2; jj++) {
      bb[jj][0] = *(const bf16x8*)(base + jj * 2048 + grp0);
      bb[jj][1] = *(const bf16x8*)(base + jj * 2048 + grp1);
    }
  };
  auto mm4 = [&](int mi, bf16x8 (&bb)[2][2], int nj) {
    #pragma unroll
    for (int ii = 0; ii < 4; ii++)
      #pragma unroll
      for (int jj = 0; jj < 2; jj++) {
        acc[mi + ii][nj + jj] = __builtin_amdgcn_mfma_f32_16x16x32_bf16(
            a[ii][0], bb[jj][0], acc[mi + ii][nj + jj], 0, 0, 0);
        acc[mi + ii][nj + jj] = __builtin_amdgcn_mfma_f32_16x16x32_bf16(
            a[ii][1], bb[jj][1], acc[mi + ii][nj + jj], 0, 0, 0);
      }
  };

#define BARX() __builtin_amdgcn_s_barrier()
#define LGKM0() do { asm volatile("s_waitcnt lgkmcnt(0)" ::: "memory"); \
                     __builtin_amdgcn_sched_barrier(0); } while (0)
#define HALF4(BC, DOA, SAB, SAK, DOB, SBB, SBK, VMN)                      \
  do {                                                                    \
    rdA(BC, 0); rdB(BC, 0, b01);                                          \
    if (DOA) stA(SAB, 0, SAK);                                            \
    BARX(); LGKM0();                                                      \
    __builtin_amdgcn_s_setprio(1); mm4(0, b01, 0);                        \
    __builtin_amdgcn_s_setprio(0); BARX();                                \
    rdB(BC, 1, b23);                                                      \
    if (DOA) stA(SAB, 1, SAK);                                            \
    BARX(); LGKM0();                                                      \
    __builtin_amdgcn_s_setprio(1); mm4(0, b23, 2);                        \
    __builtin_amdgcn_s_setprio(0); BARX();                                \
    rdA(BC, 1);                                                           \
    if (DOB) stB(SBB, 0, SBK);                                            \
    BARX(); LGKM0();                                                      \
    __builtin_amdgcn_s_setprio(1); mm4(4, b01, 0);                        \
    __builtin_amdgcn_s_setprio(0); BARX();                                \
    if (DOB) stB(SBB, 1, SBK);                                            \
    BARX();                                                               \
    __builtin_amdgcn_s_setprio(1); mm4(4, b23, 2);                        \
    __builtin_amdgcn_s_setprio(0);                                        \
    asm volatile("s_waitcnt vmcnt(" VMN ")" ::: "memory");                \
    BARX();                                                               \
  } while (0)

  const int nt = nk >> 6;
  // prologue: tile0 (8 loads) + tile1.B (4 loads); vmcnt(4) -> tile0 landed
  stA(0, 0, 0); stA(0, 1, 0);
  stB(0, 0, 0); stB(0, 1, 0);
  stB(1, 0, 1); stB(1, 1, 1);
  asm volatile("s_waitcnt vmcnt(4)" ::: "memory");
  BARX();
  int tt = 0;
  for (; tt + 2 < nt; tt += 2) {
    HALF4(0, 1, 1, tt + 1, 1, 0, tt + 2, "4");
    HALF4(1, 1, 0, tt + 2, 1, 1, tt + 3, "4");
  }
  // tail: tt = nt-2; stage only (nt-1).A, drain fully before last tile
  HALF4(0, 1, 1, tt + 1, 0, 0, 0, "0");
  HALF4(1, 0, 0, 0, 0, 0, 0, "0");
#undef HALF4
#undef LGKM0
#undef BARX
}

// ======== 256x128 4-phase mainloop (BN=128, deep-K variant for FFN2) ========
// 512 thr, 8 waves 2Mx4N, per-wave out 128x32, acc[8][2]. LDS 96KB:
// buf stride 49152 = [A 32K | B 16K]; tile t -> buf t&1.
// Per macro (2 K-tiles T,T+1; 4 phases, each {ds_read / stage / bar / lgkm /
// 16xMFMA / bar}):
//   p1: rdA0(b0)+rdB(b0); stage (T+1).A -> b1   [b1.A last read prev p4]
//   p2: rdA1(b0);         stage (T+2).B -> b0   [b0.B last read p1]; vmcnt(2)
//   p3: rdA0(b1)+rdB(b1); stage (T+2).A -> b0   [b0.A last read p2]
//   p4: rdA1(b1);         stage (T+3).B -> b1   [b1.B last read p3]; vmcnt(2)
// Issue order per macro: [A 4][B 2][A 4][B 2]; vmcnt(2)@p2 retires (T+1).A
// (needed p3), vmcnt(2)@p4 retires (T+2).B+(T+2).A (needed next p1). Last
// macro: skip future stages, vmcnt(0) at p2/p4.
__device__ __forceinline__ void mainloop_256x128(const bf16* __restrict__ A,
                                                 const bf16* __restrict__ BT,
                                                 int lda, int nk, int m0, int n0,
                                                 char* ldsb, int t,
                                                 f32x4 (&acc)[8][2]) {
  const int lane = t & 63, wave = t >> 6;
  const int l = lane & 15, quad = lane >> 4;
  const int wm = (wave >> 2) * 128, wn = (wave & 3) * 32;
  const int srow = wave * 8 + (lane >> 3);
  const int scol = ((lane & 7) ^ (lane >> 3)) * 8;
  const int grp0 = (quad ^ (l & 7)) * 16;
  const int grp1 = ((4 + quad) ^ (l & 7)) * 16;

  bf16x8 a[4][2], bb[2][2];

  auto stA = [&](int buf, int half, int kt) {
    const bf16* s = A + (size_t)(m0 + half * 128 + srow) * lda + kt * 64 + scol;
    char* d = ldsb + buf * 49152 + half * 16384 + wave * 1024;
    gl2lds16(s, d);
    gl2lds16(s + (size_t)64 * lda, d + 8192);
  };
  auto stB = [&](int buf, int kt) {
    const bf16* s = BT + (size_t)(n0 + srow) * lda + kt * 64 + scol;
    char* d = ldsb + buf * 49152 + 32768 + wave * 1024;
    gl2lds16(s, d);
    gl2lds16(s + (size_t)64 * lda, d + 8192);
  };
  auto rdA = [&](int buf, int mh) {
    const char* base = ldsb + buf * 49152 + (wm + mh * 64 + l) * 128;
    #pragma unroll
    for (int ii = 0; ii < 4; ii++) {
      a[ii][0] = *(const bf16x8*)(base + ii * 2048 + grp0);
      a[ii][1] = *(const bf16x8*)(base + ii * 2048 + grp1);
    }
  };
  auto rdB = [&](int buf) {
    const char* base = ldsb + buf * 49152 + 32768 + (wn + l) * 128;
    #pragma unroll
    for (int jj = 0; jj < 2; jj++) {
      bb[jj][0] = *(const bf16x8*)(base + jj * 2048 + grp0);
      bb[jj][1] = *(const bf16x8*)(base + jj * 2048 + grp1);
    }
  };
  auto mm = [&](int mi) {
    #pragma unroll
    for (int ii = 0; ii < 4; ii++)
      #pragma unroll
      for (int jj = 0; jj < 2; jj++) {
        acc[mi + ii][jj] = __builtin_amdgcn_mfma_f32_16x16x32_bf16(
            a[ii][0], bb[jj][0], acc[mi + ii][jj], 0, 0, 0);
        acc[mi + ii][jj] = __builtin_amdgcn_mfma_f32_16x16x32_bf16(
            a[ii][1], bb[jj][1], acc[mi + ii][jj], 0, 0, 0);
      }
  };

#define BARX() __builtin_amdgcn_s_barrier()
#define LGKM0() do { asm volatile("s_waitcnt lgkmcnt(0)" ::: "memory"); \
                     __builtin_amdgcn_sched_barrier(0); } while (0)
  const int nt = nk >> 6;  // 32; requires nt even, >= 4
  // prologue: [T0.B 2][T0.A 4][T1.B 2]; vmcnt(2) -> T0 landed (T1.B in flight)
  stB(0, 0);
  stA(0, 0, 0); stA(0, 1, 0);
  stB(1, 1);
  asm volatile("s_waitcnt vmcnt(2)" ::: "memory");
  BARX();
  for (int T = 0; T < nt; T += 2) {
    int lastm = (T + 2 >= nt);
    // p1: compute T (A0-sub), stage (T+1).A -> buf1
    rdA(0, 0); rdB(0);
    stA(1, 0, T + 1); stA(1, 1, T + 1);
    BARX(); LGKM0();
    __builtin_amdgcn_s_setprio(1); mm(0); __builtin_amdgcn_s_setprio(0);
    BARX();
    // p2: compute T (A1-sub), stage (T+2).B -> buf0
    rdA(0, 1);
    if (!lastm) stB(0, T + 2);
    BARX(); LGKM0();
    __builtin_amdgcn_s_setprio(1); mm(4); __builtin_amdgcn_s_setprio(0);
    if (!lastm) asm volatile("s_waitcnt vmcnt(2)" ::: "memory");
    else        asm volatile("s_waitcnt vmcnt(0)" ::: "memory");
    BARX();
    // p3: compute T+1 (A0-sub), stage (T+2).A -> buf0
    rdA(1, 0); rdB(1);
    if (!lastm) { stA(0, 0, T + 2); stA(0, 1, T + 2); }
    BARX(); LGKM0();
    __builtin_amdgcn_s_setprio(1); mm(0); __builtin_amdgcn_s_setprio(0);
    BARX();
    // p4: compute T+1 (A1-sub), stage (T+3).B -> buf1
    rdA(1, 1);
    if (!lastm) stB(1, T + 3);
    BARX(); LGKM0();
    __builtin_amdgcn_s_setprio(1); mm(4); __builtin_amdgcn_s_setprio(0);
    if (!lastm) asm volatile("s_waitcnt vmcnt(2)" ::: "memory");
    else        asm volatile("s_waitcnt vmcnt(0)" ::: "memory");
    BARX();
  }
#undef LGKM0
#undef BARX
}

// ---------------- FFN1: act bf16 = gelu(h @ W1 + b1), N=4096 K=1024 ---------
__global__ __launch_bounds__(512, 2) void gemm_ffn1(const bf16* __restrict__ A,
                                                    const bf16* __restrict__ BT,
                                                    const float* __restrict__ bias,
                                                    bf16* __restrict__ out,
                                                    int N, int K) {
  extern __shared__ char lds[];
  int t = threadIdx.x;
  int nf = swz8(blockIdx.x, gridDim.x);
  int n0 = (nf & 15) * 256, m0 = (nf >> 4) * 256;
  f32x4 acc[8][4];
  #pragma unroll
  for (int i = 0; i < 8; i++)
    #pragma unroll
    for (int j = 0; j < 4; j++) acc[i][j] = (f32x4){0.f, 0.f, 0.f, 0.f};
  mainloop_256(A, BT, K, K, m0, n0, lds, t, acc);

  int lane = t & 63, wave = t >> 6;
  int l = lane & 15, quad = lane >> 4;
  int wm = (wave >> 2) * 128, wn = (wave & 3) * 64;
  int r4 = quad * 4;
  unsigned short* os = reinterpret_cast<unsigned short*>(out);
  #pragma unroll
  for (int i = 0; i < 8; i++)
    #pragma unroll
    for (int j = 0; j < 4; j++) {
      int col = n0 + wn + j * 16 + l;
      float bval = bias[col];
      #pragma unroll
      for (int r = 0; r < 4; r++) {
        int row = m0 + wm + i * 16 + r4 + r;
        os[(size_t)row * N + col] = f2bf_rne(gelu_fast(acc[i][j][r] + bval));
      }
    }
}

// ------- FFN2 split-K z=2 (256x128 deep-K): partial[z] = act[:,z]@W2T[:,z] --
// M=4096 N=1024 K=4096; z in {0,1}, each K=2048 (nt=32, 2x deeper pipeline).
// Grid 256 = 8n x 16m x 2z = 1 block/CU. LDS 96KB.
__global__ __launch_bounds__(512, 2) void gemm_ffn2(const bf16* __restrict__ A,
                                                    const bf16* __restrict__ BT,
                                                    unsigned short* __restrict__ p0,
                                                    unsigned short* __restrict__ p1) {
  extern __shared__ char lds[];
  int t = threadIdx.x;
  int nf = swz8(blockIdx.x, gridDim.x);
  int n0 = (nf & 7) * 128, m0 = ((nf >> 3) & 15) * 256;
  int z = nf >> 7;
  f32x4 acc[8][2];
  #pragma unroll
  for (int i = 0; i < 8; i++)
    #pragma unroll
    for (int j = 0; j < 2; j++) acc[i][j] = (f32x4){0.f, 0.f, 0.f, 0.f};
  mainloop_256x128(A + z * 2048, BT + z * 2048, 4096, 2048, m0, n0, lds, t, acc);

  unsigned short* p = z ? p1 : p0;
  int lane = t & 63, wave = t >> 6;
  int l = lane & 15, quad = lane >> 4;
  int wm = (wave >> 2) * 128, wn = (wave & 3) * 32;
  int r4 = quad * 4;
  #pragma unroll
  for (int i = 0; i < 8; i++)
    #pragma unroll
    for (int j = 0; j < 2; j++) {
      int col = n0 + wn + j * 16 + l;
      #pragma unroll
      for (int r = 0; r < 4; r++) {
        int row = m0 + wm + i * 16 + r4 + r;
        p[(size_t)row * 1024 + col] = f2bf_rne(acc[i][j][r]);
      }
    }
}

// -------- FFN2 reduce: out f32 = p0 + p1 + bias + x1 --------
__global__ __launch_bounds__(256) void reduce_ffn2(const unsigned short* __restrict__ p0,
                                                   const unsigned short* __restrict__ p1,
                                                   const float* __restrict__ x1,
                                                   const float* __restrict__ bias,
                                                   float* __restrict__ out) {
  int row = blockIdx.x, t = threadIdx.x;
  size_t base = (size_t)row * 1024;
  ushort4 a = ((const ushort4*)(p0 + base))[t];
  ushort4 b = ((const ushort4*)(p1 + base))[t];
  float4 xv = ((const float4*)(x1 + base))[t];
  float4 bv = ((const float4*)bias)[t];
  float4 o;
  o.x = (bf2f(a.x) + bf2f(b.x)) + xv.x + bv.x;
  o.y = (bf2f(a.y) + bf2f(b.y)) + xv.y + bv.y;
  o.z = (bf2f(a.z) + bf2f(b.z)) + xv.z + bv.z;
  o.w = (bf2f(a.w) + bf2f(b.w)) + xv.w + bv.w;
  ((float4*)(out + base))[t] = o;
}

// ------------- fused QKV GEMM: N=3072 (q|k|v) -------------
// k written pre-scaled by SCALE_CS (softmax scale folded in);
// v written transposed via LDS staging -> coalesced 512B row writes.
__global__ __launch_bounds__(512, 2) void gemm_qkv(const bf16* __restrict__ A,
                                                   const bf16* __restrict__ BT,
                                                   const float* __restrict__ bq,
                                                   const float* __restrict__ bk,
                                                   const float* __restrict__ bv,
                                                   bf16* __restrict__ qb,
                                                   bf16* __restrict__ kb,
                                                   bf16* __restrict__ vt,
                                                   int K) {
  extern __shared__ char lds[];
  int t = threadIdx.x;
  int nf = swz8(blockIdx.x, gridDim.x);
  int n0 = (nf % 12) * 256, m0 = (nf / 12) * 256;
  f32x4 acc[8][4];
  #pragma unroll
  for (int i = 0; i < 8; i++)
    #pragma unroll
    for (int j = 0; j < 4; j++) acc[i][j] = (f32x4){0.f, 0.f, 0.f, 0.f};
  mainloop_256(A, BT, K, K, m0, n0, lds, t, acc);

  int lane = t & 63, wave = t >> 6;
  int l = lane & 15, quad = lane >> 4;
  int wm = (wave >> 2) * 128, wn = (wave & 3) * 64;
  int sect = n0 >> 10;  // 0=q 1=k 2=v (BN=256 divides 1024 sections)
  const float* bias = sect == 0 ? bq : (sect == 1 ? bk : bv);
  int r4 = quad * 4;
  if (sect < 2) {
    bf16* o = sect == 0 ? qb : kb;
    unsigned short* os = reinterpret_cast<unsigned short*>(o);
    float scl = sect == 1 ? SCALE_CS : 1.0f;
    #pragma unroll
    for (int i = 0; i < 8; i++)
      #pragma unroll
      for (int j = 0; j < 4; j++) {
        int col = n0 + wn + j * 16 + l;
        int c1 = col & 1023;
        float bval = bias[c1];
        int row0 = m0 + wm + i * 16 + r4;
        #pragma unroll
        for (int r = 0; r < 4; r++)
          os[(size_t)(row0 + r) * 1024 + c1] = f2bf_rne((acc[i][j][r] + bval) * scl);
      }
  } else {
    // stage (c, t) transposed tile in LDS (8B-group XOR swizzle), then
    // each wave writes full 512B vt rows, coalesced.
    unsigned short* Ls = (unsigned short*)lds;
    #pragma unroll
    for (int i = 0; i < 8; i++)
      #pragma unroll
      for (int j = 0; j < 4; j++) {
        int c1l = wn + j * 16 + l;                  // 0..255 (local d-col)
        float bval = bias[(n0 - 2048) + c1l];
        ushort4 pk;
        pk.x = f2bf_rne(acc[i][j][0] + bval);
        pk.y = f2bf_rne(acc[i][j][1] + bval);
        pk.z = f2bf_rne(acc[i][j][2] + bval);
        pk.w = f2bf_rne(acc[i][j][3] + bval);
        int gq = ((wm + i * 16) >> 2) + quad;       // 8B group (4 rows) 0..63
        *(ushort4*)((char*)Ls + c1l * 512 + ((gq ^ (c1l & 15)) << 3)) = pk;
      }
    __syncthreads();
    int bb = m0 >> 11, t0b = m0 & 2047;
    size_t vbase = ((size_t)(bb * 1024 + (n0 - 2048))) * 2048 + t0b;
    #pragma unroll 4
    for (int it2 = 0; it2 < 32; it2++) {
      int c1row = it2 * 8 + wave;
      uint2 v = *(const uint2*)((char*)Ls + c1row * 512 +
                                ((lane ^ (c1row & 15)) << 3));
      *(uint2*)((unsigned short*)vt + vbase + (size_t)c1row * 2048 + lane * 4) = v;
    }
  }
}

// ---------------- MFMA flash attention v9 (unchanged from r10) ----------------
__global__ __launch_bounds__(512, 4) void attn_mfma(const bf16* __restrict__ qb,
                                                    const bf16* __restrict__ kb,
                                                    const bf16* __restrict__ vt,
                                                    const float* __restrict__ x,
                                                    float* __restrict__ x1) {
  extern __shared__ char alds[];
  char* KVb = alds;           // 64KB: g*32768 + buf*16384 + (K:0|V:8192) + w4*2048
  char* Pb  = alds + 65536;   // 16KB: wave*2048, row l stride 128B
  int t = threadIdx.x;
  int nf = swz8(blockIdx.x, 1024);
  int chunk = nf >> 7, local = nf & 127;
  int y = local >> 2;                 // 0..31, ascending = largest-first
  int bh = chunk * 4 + (local & 3);   // 4 heads per XCD chunk
  int b = bh >> 4, h = bh & 15;
  size_t qk_base = (size_t)b * 2048 * 1024 + (size_t)h * 64;
  size_t vt_base = (size_t)bh * 64 * 2048;
  int lane = t & 63, wave = t >> 6;
  int g = wave >> 2, w4 = wave & 3;
  int l = lane & 15, quad = lane >> 4;
  int sw = l & 7;
  int srow8 = lane >> 3;                       // staging row-in-8 (0..7)
  int scol = ((lane & 7) ^ srow8) * 8;         // swizzled source col (elems)
  int it = 31 - y;                             // largest first
  int i0 = it * 64;
  int njt = it + 1;
  int iblk = i0 + w4 * 16;

  bf16x8 ones;
  #pragma unroll
  for (int z = 0; z < 8; z++) ones[z] = (short)0x3F80;  // bf16 1.0

  // prologue: waves 0-3 stage Q (into P region) + group0 KV tile0;
  // waves 4-7 stage group1 KV tile1 (if it exists)
  if (g == 0) {
    #pragma unroll
    for (int c = 0; c < 2; c++) {
      int rr = w4 * 16 + c * 8 + srow8;
      gl2lds16(kb + qk_base + (size_t)(i0 + rr) * 1024 + scol,
               Pb + w4 * 2048 + c * 1024);
      gl2lds16(qb + qk_base + (size_t)rr * 1024 + scol,
               KVb + w4 * 2048 + c * 1024);
      gl2lds16(vt + vt_base + (size_t)rr * 2048 + scol,
               KVb + 8192 + w4 * 2048 + c * 1024);
    }
  } else if (njt > 1) {
    #pragma unroll
    for (int c = 0; c < 2; c++) {
      int rr = w4 * 16 + c * 8 + srow8;
      gl2lds16(qb + qk_base + (size_t)(64 + rr) * 1024 + scol,
               KVb + 32768 + w4 * 2048 + c * 1024);
      gl2lds16(vt + vt_base + (size_t)rr * 2048 + 64 + scol,
               KVb + 32768 + 8192 + w4 * 2048 + c * 1024);
    }
  }
  __syncthreads();  // drains vmcnt: Q + first tiles visible

  const char* qr = Pb + w4 * 2048 + l * 128;
  bf16x8 qf0 = *(const bf16x8*)(qr + ((quad ^ sw) * 16));
  bf16x8 qf1 = *(const bf16x8*)(qr + (((4 + quad) ^ sw) * 16));
  __syncthreads();  // all waves hold Q in regs; P region may be overlaid now

  f32x4 Oacc[4], Ol;
  #pragma unroll
  for (int dt = 0; dt < 4; dt++) Oacc[dt] = (f32x4){0.f, 0.f, 0.f, 0.f};
  Ol = (f32x4){0.f, 0.f, 0.f, 0.f};

  char* Pw = Pb + wave * 2048 + l * 128;  // own-wave P row base
  char* KVg = KVb + g * 32768;
  int nstep = (njt + 1) >> 1;
  int buf = 0;
  for (int s = 0; s < nstep; s++) {
    int jt = 2 * s + g;
    // prefetch my group's tile jt+2 into other buffer
    if (jt + 2 < njt) {
      int j1 = (jt + 2) * 64;
      #pragma unroll
      for (int c = 0; c < 2; c++) {
        int rr = w4 * 16 + c * 8 + srow8;
        gl2lds16(qb + qk_base + (size_t)(j1 + rr) * 1024 + scol,
                 KVg + (buf ^ 1) * 16384 + w4 * 2048 + c * 1024);
        gl2lds16(vt + vt_base + (size_t)rr * 2048 + j1 + scol,
                 KVg + (buf ^ 1) * 16384 + 8192 + w4 * 2048 + c * 1024);
      }
    }
    if (jt < njt) {
      int j0v = jt * 64;
      // S^T per nt: A = rows from qb (m=j), B = pre-scaled frag from kb (n=i)
      const bf16* Kb = (const bf16*)(KVg + buf * 16384);
      #pragma unroll
      for (int nt = 0; nt < 4; nt++) {
        int jb = j0v + nt * 16;
        uint2 pk;
        if (jb > iblk + 15) {  // fully masked
          pk.x = 0u; pk.y = 0u;
        } else {
          const bf16* kr = Kb + (nt * 16 + l) * 64;
          bf16x8 kf0 = *(const bf16x8*)(kr + ((quad ^ sw) * 8));
          bf16x8 kf1 = *(const bf16x8*)(kr + (((4 + quad) ^ sw) * 8));
          f32x4 sv = (f32x4){0.f, 0.f, 0.f, 0.f};
          sv = __builtin_amdgcn_mfma_f32_16x16x32_bf16(kf0, qf0, sv, 0, 0, 0);
          sv = __builtin_amdgcn_mfma_f32_16x16x32_bf16(kf1, qf1, sv, 0, 0, 0);
          float p0, p1, p2, p3;
          if (jb + 15 <= iblk) {  // fully unmasked
            p0 = __builtin_amdgcn_exp2f(sv[0]);
            p1 = __builtin_amdgcn_exp2f(sv[1]);
            p2 = __builtin_amdgcn_exp2f(sv[2]);
            p3 = __builtin_amdgcn_exp2f(sv[3]);
          } else {                // diagonal straddle
            int i_ = iblk + l, jbase = jb + quad * 4;
            p0 = (jbase + 0 > i_) ? 0.f : __builtin_amdgcn_exp2f(sv[0]);
            p1 = (jbase + 1 > i_) ? 0.f : __builtin_amdgcn_exp2f(sv[1]);
            p2 = (jbase + 2 > i_) ? 0.f : __builtin_amdgcn_exp2f(sv[2]);
            p3 = (jbase + 3 > i_) ? 0.f : __builtin_amdgcn_exp2f(sv[3]);
          }
          union { __hip_bfloat162 h2; unsigned u; } c0u, c1u;
          c0u.h2 = __float22bfloat162_rn(make_float2(p0, p1));
          c1u.h2 = __float22bfloat162_rn(make_float2(p2, p3));
          pk.x = c0u.u; pk.y = c1u.u;
        }
        // P row byte offset: 16B group g16=nt*2+(quad>>1) swizzled by sw
        *(uint2*)(Pw + (((nt * 2 + (quad >> 1)) ^ sw) << 4) + ((quad & 1) << 3)) = pk;
      }
      asm volatile("s_waitcnt lgkmcnt(0)" ::: "memory");  // own-wave P only

      // PV: A = P rows (m=i), B = V rows (n=d); +ones-MFMA for row sums
      bf16x8 ap0 = *(const bf16x8*)(Pw + ((quad ^ sw) << 4));
      bf16x8 ap1 = *(const bf16x8*)(Pw + (((4 + quad) ^ sw) << 4));
      const bf16* Vb = (const bf16*)(KVg + buf * 16384 + 8192);
      #pragma unroll
      for (int dt = 0; dt < 4; dt++) {
        const bf16* vr = Vb + (dt * 16 + l) * 64;
        bf16x8 bv0 = *(const bf16x8*)(vr + ((quad ^ sw) * 8));
        bf16x8 bv1 = *(const bf16x8*)(vr + (((4 + quad) ^ sw) * 8));
        Oacc[dt] = __builtin_amdgcn_mfma_f32_16x16x32_bf16(ap0, bv0, Oacc[dt], 0, 0, 0);
        Oacc[dt] = __builtin_amdgcn_mfma_f32_16x16x32_bf16(ap1, bv1, Oacc[dt], 0, 0, 0);
      }
      Ol = __builtin_amdgcn_mfma_f32_16x16x32_bf16(ap0, ones, Ol, 0, 0, 0);
      Ol = __builtin_amdgcn_mfma_f32_16x16x32_bf16(ap1, ones, Ol, 0, 0, 0);
    }
    __syncthreads();  // drains prefetch (vmcnt) + group done with buf
    buf ^= 1;
  }

  // in-block combine: group1 -> LDS (KV region now free) -> group0 adds
  float* F = (float*)KVb;
  int fbase = w4 * 1280;
  if (g == 1) {
    #pragma unroll
    for (int dt = 0; dt < 4; dt++)
      #pragma unroll
      for (int r = 0; r < 4; r++)
        F[fbase + (dt * 4 + r) * 64 + lane] = Oacc[dt][r];
    #pragma unroll
    for (int r = 0; r < 4; r++)
      F[fbase + 1024 + r * 64 + lane] = Ol[r];
  }
  __syncthreads();
  if (g == 0) {
    #pragma unroll
    for (int dt = 0; dt < 4; dt++)
      #pragma unroll
      for (int r = 0; r < 4; r++)
        Oacc[dt][r] += F[fbase + (dt * 4 + r) * 64 + lane];
    #pragma unroll
    for (int r = 0; r < 4; r++)
      Ol[r] += F[fbase + 1024 + r * 64 + lane];
    // lane (quad,l): Ol[r] = rowsum for row quad*4+r (same in every col l)
    #pragma unroll
    for (int r = 0; r < 4; r++) {
      float inv = 1.0f / Ol[r];
      int row = iblk + quad * 4 + r;
      size_t gi = qk_base + (size_t)row * 1024;
      #pragma unroll
      for (int dt = 0; dt < 4; dt++) {
        int d = dt * 16 + l;
        x1[gi + d] = x[gi + d] + Oacc[dt][r] * inv;
      }
    }
  }
}

extern "C" void kernel_launch(void* const* d_in, const int* in_sizes, int n_in,
                              void* d_out, int out_size, void* d_ws, size_t ws_size,
                              hipStream_t stream) {
  const float* x    = (const float*)d_in[0];
  const float* ln1g = (const float*)d_in[1];
  const float* ln1b = (const float*)d_in[2];
  const float* Wq   = (const float*)d_in[3];
  const float* bq   = (const float*)d_in[4];
  const float* Wk   = (const float*)d_in[5];
  const float* bk   = (const float*)d_in[6];
  const float* Wv   = (const float*)d_in[7];
  const float* bv   = (const float*)d_in[8];
  const float* ln2g = (const float*)d_in[9];
  const float* ln2b = (const float*)d_in[10];
  const float* W1   = (const float*)d_in[11];
  const float* b1   = (const float*)d_in[12];
  const float* W2   = (const float*)d_in[13];
  const float* b2   = (const float*)d_in[14];

  char* ws = (char*)d_ws;
  float* x1  = (float*)(ws + 0);            // 16 MB f32 [4096][1024]
  bf16* h    = (bf16*)(ws + 16777216);      //  8 MB bf16 [4096][1024]
  bf16* WqkT = (bf16*)(ws + 25165824);      //  6 MB bf16 [3072][1024] (q|k|v)
  bf16* W1T  = (bf16*)(ws + 31457280);      //  8 MB [4096][1024]
  bf16* W2T  = (bf16*)(ws + 39845888);      //  8 MB [1024][4096]
  bf16* qb   = (bf16*)(ws + 48234496);      //  8 MB [4096][1024]  (reused: FFN2 partial 0)
  bf16* kb   = (bf16*)(ws + 56623104);      //  8 MB [4096][1024]  (reused: FFN2 partial 1)
  bf16* vt   = (bf16*)(ws + 65011712);      //  8 MB [b,h,d,t] = [2048][2048]
  bf16* act  = (bf16*)(ws + 73400320);      // 32 MB [4096][4096]

  static bool s_attr_done = false;
  if (!s_attr_done) {
    hipFuncSetAttribute(reinterpret_cast<const void*>(gemm_qkv),
                        hipFuncAttributeMaxDynamicSharedMemorySize, 131072);
    hipFuncSetAttribute(reinterpret_cast<const void*>(gemm_ffn1),
                        hipFuncAttributeMaxDynamicSharedMemorySize, 131072);
    hipFuncSetAttribute(reinterpret_cast<const void*>(gemm_ffn2),
                        hipFuncAttributeMaxDynamicSharedMemorySize, 98304);
    hipFuncSetAttribute(reinterpret_cast<const void*>(attn_mfma),
                        hipFuncAttributeMaxDynamicSharedMemorySize, 81920);
    s_attr_done = true;
  }

  prep_fused<<<15360, 256, 0, stream>>>(x, ln1g, ln1b, h,
                                        Wq, Wk, Wv, W1, W2, WqkT, W1T, W2T);
  gemm_qkv<<<192, 512, 131072, stream>>>(h, WqkT, bq, bk, bv, qb, kb, vt, 1024);
  attn_mfma<<<1024, 512, 81920, stream>>>(qb, kb, vt, x, x1);
  ln_kernel<<<4096, 256, 0, stream>>>(x1, ln2g, ln2b, h);
  gemm_ffn1<<<256, 512, 131072, stream>>>(h, W1T, b1, act, 4096, 1024);
  gemm_ffn2<<<256, 512, 98304, stream>>>(act, W2T,
      (unsigned short*)qb, (unsigned short*)kb);
  reduce_ffn2<<<4096, 256, 0, stream>>>((const unsigned short*)qb, (const unsigned short*)kb,
                                        x1, b2, (float*)d_out);
}